// Round 4
// baseline (1814.481 us; speedup 1.0000x reference)
//
#include <hip/hip_runtime.h>
#include <hip/hip_bf16.h>

// Multi-relational GCN, 4 layers. Round 4:
//  - two-phase bucketed CSR fill (kills the 8B-random-scatter 64B-line write amp)
//  - one GEMM + one SpMM launch per layer (128-wide bf16 XW, as round 3)
// relation r = 2*i + j: dst type i = r>>1, src type j = r&1.
// Segments 0..3 = adj1 (layers 1-2), 4..7 = adj2 (layers 3-4).
// Buckets: RB=64 dst rows per bucket; NBper = ceil(N/64) buckets per segment.

#define DOUT 64
#define OUTW 128
#define RB_LOG 6
#define RB 64

__device__ __forceinline__ float bf2f(unsigned short u) {
    return __uint_as_float((unsigned)u << 16);
}

// ---------------- histogram of dst rows into cnt[s*N + row], s = 0..7
__global__ __launch_bounds__(256) void k_hist(
    const int* __restrict__ rows1, const int* __restrict__ rows2,
    int E, int N, int* __restrict__ cnt)
{
    const int s = blockIdx.y;
    const int* rows = (s < 4) ? rows1 : rows2;
    const int rl = s & 3;
    const int e = blockIdx.x * 256 + threadIdx.x;
    if (e < E) atomicAdd(&cnt[s * N + rows[(size_t)rl * E + e]], 1);
}

// ---------------- exclusive scan, 3-kernel
__global__ __launch_bounds__(256) void k_scan1(
    const int* __restrict__ cnt, int M, int* __restrict__ out, int* __restrict__ partials)
{
    __shared__ int sm[256];
    const int i = blockIdx.x * 256 + threadIdx.x;
    const int x = (i < M) ? cnt[i] : 0;
    sm[threadIdx.x] = x;
    __syncthreads();
    for (int off = 1; off < 256; off <<= 1) {
        int t = (threadIdx.x >= off) ? sm[threadIdx.x - off] : 0;
        __syncthreads();
        sm[threadIdx.x] += t;
        __syncthreads();
    }
    if (i < M) out[i] = sm[threadIdx.x] - x;
    if (threadIdx.x == 255) partials[blockIdx.x] = sm[255];
}

__global__ __launch_bounds__(256) void k_scan2(int* __restrict__ partials, int nb)
{
    __shared__ int sm[256];
    __shared__ int carry_s;
    if (threadIdx.x == 0) carry_s = 0;
    __syncthreads();
    for (int base = 0; base < nb; base += 256) {
        const int i = base + threadIdx.x;
        const int x = (i < nb) ? partials[i] : 0;
        sm[threadIdx.x] = x;
        __syncthreads();
        for (int off = 1; off < 256; off <<= 1) {
            int t = (threadIdx.x >= off) ? sm[threadIdx.x - off] : 0;
            __syncthreads();
            sm[threadIdx.x] += t;
            __syncthreads();
        }
        const int carry = carry_s;
        const int incl  = sm[threadIdx.x];
        __syncthreads();
        if (i < nb) partials[i] = incl - x + carry;
        if (threadIdx.x == 255) carry_s = carry + incl;
        __syncthreads();
    }
}

__global__ __launch_bounds__(256) void k_scan3(
    int* __restrict__ row_ptr, int* __restrict__ cursor,
    const int* __restrict__ partials, int M, int total)
{
    const int i = blockIdx.x * 256 + threadIdx.x;
    if (i < M) {
        const int v = row_ptr[i] + partials[blockIdx.x];
        row_ptr[i] = v;
        cursor[i]  = v;   // used by fallback direct-fill only; harmless otherwise
    }
    if (i == 0) row_ptr[M] = total;
}

// ---------------- bucket cursor init: bcur[seg*NBper + b] = row_ptr[seg*N + b*RB]
__global__ __launch_bounds__(256) void k_binit(
    const int* __restrict__ row_ptr, int* __restrict__ bcur, int N, int NBper, int NB)
{
    const int i = blockIdx.x * 256 + threadIdx.x;
    if (i >= NB) return;
    const int seg = i / NBper;
    const int b   = i - seg * NBper;
    bcur[i] = row_ptr[(size_t)seg * N + (b << RB_LOG)];
}

// ---------------- phase A: scatter edges to bucket fronts (sequential cursors)
__global__ __launch_bounds__(256) void k_fillA(
    const int* __restrict__ rows1, const int* __restrict__ cols1, const float* __restrict__ vals1,
    const int* __restrict__ rows2, const int* __restrict__ cols2, const float* __restrict__ vals2,
    int E, int NBper, int* __restrict__ bcur,
    int2* __restrict__ stg, unsigned char* __restrict__ srl)
{
    const int s = blockIdx.y;
    const int e = blockIdx.x * 256 + threadIdx.x;
    if (e >= E) return;
    const int rl = s & 3;
    const int* rows = (s < 4) ? rows1 : rows2;
    const int* cols = (s < 4) ? cols1 : cols2;
    const float* vals = (s < 4) ? vals1 : vals2;
    const size_t idx = (size_t)rl * E + e;
    const int row = rows[idx];
    const int bg  = s * NBper + (row >> RB_LOG);
    const int pos = atomicAdd(&bcur[bg], 1);
    stg[pos] = make_int2(cols[idx], __float_as_int(vals[idx]));
    srl[pos] = (unsigned char)(row & (RB - 1));
}

// ---------------- phase B: one wave per bucket; ballot-rank within-row order,
// scatter (col,val) to exact CSR positions inside the bucket's L2-local window.
__global__ __launch_bounds__(256) void k_fillB(
    const int2* __restrict__ stg, const unsigned char* __restrict__ srl,
    const int* __restrict__ row_ptr, int N, int NBper, int NB,
    int2* __restrict__ cv)
{
    __shared__ int cntS[4][RB];
    const int wv   = threadIdx.x >> 6;
    const int lane = threadIdx.x & 63;
    const int wid  = blockIdx.x * 4 + wv;
    if (wid >= NB) return;
    const int seg = wid / NBper;
    const int b   = wid - seg * NBper;
    const int r0  = b << RB_LOG;
    const int nrows = min(RB, N - r0);
    const int* rp = row_ptr + (size_t)seg * N + r0;
    const int base = rp[0];
    const int endp = row_ptr[(size_t)seg * N + min(r0 + RB, N)];

    cntS[wv][lane] = (lane < nrows) ? rp[lane] : 0;  // per-row next-slot cursor

    for (int t0 = base; t0 < endp; t0 += 64) {
        const int t = t0 + lane;
        const bool valid = (t < endp);
        int2 e = valid ? stg[t] : make_int2(0, 0);
        const int key = valid ? (int)srl[t] : (64 + lane);  // 7-bit; invalid unique

        unsigned long long eq = ~0ull;
#pragma unroll
        for (int bit = 0; bit < 7; ++bit) {
            const int kb = (key >> bit) & 1;
            const unsigned long long m = __ballot(kb);
            eq &= kb ? m : ~m;
        }
        const unsigned long long lt = (1ull << lane) - 1ull;
        const int rank = __popcll(eq & lt);
        const int tot  = __popcll(eq);

        if (valid) {
            const int basepos = cntS[wv][key];      // broadcast read
            const int mypos = basepos + rank;
            if (rank == tot - 1) cntS[wv][key] = mypos + 1;
            cv[mypos] = e;                          // scatter within ~5KB window
        }
    }
}

// ---------------- fallback: direct fill (round-3 path), needs row cursor array
__global__ __launch_bounds__(256) void k_fill_direct(
    const int* __restrict__ rows1, const int* __restrict__ cols1, const float* __restrict__ vals1,
    const int* __restrict__ rows2, const int* __restrict__ cols2, const float* __restrict__ vals2,
    int E, int N, int* __restrict__ cursor, int2* __restrict__ cv)
{
    const int s = blockIdx.y;
    const int e = blockIdx.x * 256 + threadIdx.x;
    if (e >= E) return;
    const int rl = s & 3;
    const int* rows = (s < 4) ? rows1 : rows2;
    const int* cols = (s < 4) ? cols1 : cols2;
    const float* vals = (s < 4) ? vals1 : vals2;
    const size_t idx = (size_t)rl * E + e;
    const int row = rows[idx];
    const int pos = atomicAdd(&cursor[s * N + row], 1);
    cv[pos] = make_int2(cols[idx], __float_as_int(vals[idx]));
}

// ---------------- dense transform: XW2[slice][n][0:64] = H_j W_j(dst0),
//                  [64:128] = H_j W_{2+j}(dst1);  bf16 output, register tiled.
template<int RELU>
__global__ __launch_bounds__(256) void k_gemm(
    const float* __restrict__ H,           // [2, N, d_in]
    const float* __restrict__ Wl,          // [4, d_in, 64]
    __hip_bfloat16* __restrict__ XW2,      // [nslice, N, 128]
    int N, int d_in, int joff)
{
    const int slice = blockIdx.y;
    const int j     = joff + slice;        // source node type
    const int col   = threadIdx.x & 63;
    const int half  = (threadIdx.x >> 6) & 1;
    const int rg    = threadIdx.x >> 7;
    const int row0  = blockIdx.x * 16 + rg * 8;

    const float* Hb = H  + (size_t)j * N * d_in;
    const float* Wb = Wl + (size_t)(half ? (2 + j) : j) * d_in * DOUT;

    int rowc[8];
#pragma unroll
    for (int m = 0; m < 8; ++m) {
        int row = row0 + m;
        rowc[m] = (row < N) ? row : (N - 1);
    }

    float acc[8];
#pragma unroll
    for (int m = 0; m < 8; ++m) acc[m] = 0.f;

#pragma unroll 2
    for (int k = 0; k < d_in; k += 4) {
        const float w0 = Wb[(k + 0) * DOUT + col];
        const float w1 = Wb[(k + 1) * DOUT + col];
        const float w2 = Wb[(k + 2) * DOUT + col];
        const float w3 = Wb[(k + 3) * DOUT + col];
#pragma unroll
        for (int m = 0; m < 8; ++m) {
            float4 h4 = *reinterpret_cast<const float4*>(Hb + (size_t)rowc[m] * d_in + k);
            if (RELU) {
                h4.x = fmaxf(h4.x, 0.f); h4.y = fmaxf(h4.y, 0.f);
                h4.z = fmaxf(h4.z, 0.f); h4.w = fmaxf(h4.w, 0.f);
            }
            acc[m] = fmaf(h4.x, w0, fmaf(h4.y, w1, fmaf(h4.z, w2, fmaf(h4.w, w3, acc[m]))));
        }
    }

#pragma unroll
    for (int m = 0; m < 8; ++m) {
        const int row = row0 + m;
        if (row < N)
            XW2[((size_t)slice * N + row) * OUTW + half * DOUT + col] =
                __float2bfloat16(acc[m]);
    }
}

// ---------------- CSR SpMM: one wave per dst row; sums over 1 or 2 segments.
__global__ __launch_bounds__(256) void k_spmm(
    const int* __restrict__ row_ptr, int set4,
    const int2* __restrict__ cv,
    const unsigned short* __restrict__ XW2,   // bf16 [nslice, N, 128]
    float* __restrict__ out,                  // [2, N, 64]
    int N, int two_src, int jsel, int beta)
{
    const int i    = blockIdx.y;
    const int n    = blockIdx.x * 4 + (threadIdx.x >> 6);
    const int lane = threadIdx.x & 63;
    if (n >= N) return;

    float acc = beta ? out[((size_t)i * N + n) * DOUT + lane] : 0.f;

    const int nsrc = two_src ? 2 : 1;
    for (int js = 0; js < nsrc; ++js) {
        const int seg = set4 + 2 * i + (two_src ? js : jsel);
        const int* rp = row_ptr + (size_t)seg * N;
        const unsigned short* xw = XW2 + (two_src ? (size_t)js * N * OUTW : 0)
                                       + (size_t)i * DOUT + lane;
        const int s = rp[n];
        const int e = rp[n + 1];

        int t = s;
        for (; t + 3 < e; t += 4) {
            const int2 p0 = cv[t + 0];
            const int2 p1 = cv[t + 1];
            const int2 p2 = cv[t + 2];
            const int2 p3 = cv[t + 3];
            const float x0 = bf2f(xw[(size_t)p0.x * OUTW]);
            const float x1 = bf2f(xw[(size_t)p1.x * OUTW]);
            const float x2 = bf2f(xw[(size_t)p2.x * OUTW]);
            const float x3 = bf2f(xw[(size_t)p3.x * OUTW]);
            acc = fmaf(__int_as_float(p0.y), x0, acc);
            acc = fmaf(__int_as_float(p1.y), x1, acc);
            acc = fmaf(__int_as_float(p2.y), x2, acc);
            acc = fmaf(__int_as_float(p3.y), x3, acc);
        }
        for (; t < e; ++t) {
            const int2 p = cv[t];
            acc = fmaf(__int_as_float(p.y), bf2f(xw[(size_t)p.x * OUTW]), acc);
        }
    }

    out[((size_t)i * N + n) * DOUT + lane] = acc;
}

extern "C" void kernel_launch(void* const* d_in, const int* in_sizes, int n_in,
                              void* d_out, int out_size, void* d_ws, size_t ws_size,
                              hipStream_t stream) {
    const float* feat      = (const float*)d_in[0];
    const int*   adj1_rows = (const int*)  d_in[1];
    const int*   adj1_cols = (const int*)  d_in[2];
    const float* adj1_vals = (const float*)d_in[3];
    const int*   adj2_rows = (const int*)  d_in[4];
    const int*   adj2_cols = (const int*)  d_in[5];
    const float* adj2_vals = (const float*)d_in[6];
    const float* W1        = (const float*)d_in[7];
    const float* W2        = (const float*)d_in[8];
    const float* W3        = (const float*)d_in[9];
    const float* W4        = (const float*)d_in[10];

    const int E = in_sizes[1] / 4;              // 500000
    const int F = in_sizes[7] / (4 * DOUT);     // 128
    const int N = in_sizes[0] / (2 * F);        // 50000
    const int M = 8 * N;
    const int nb1 = (M + 255) / 256;
    const int NBper = (N + RB - 1) >> RB_LOG;   // buckets per segment
    const int NB = 8 * NBper;

    auto align256 = [](size_t x) { return (x + 255) & ~(size_t)255; };

    // fixed region
    const size_t cv_b  = align256((size_t)8 * E * sizeof(int2));        // 32 MB
    const size_t rp_b  = align256(((size_t)M + 8) * sizeof(int));       // 1.6 MB
    const size_t cnt_b = align256((size_t)M * sizeof(int));             // 1.6 MB (cursor in fallback)
    const size_t bc_b  = align256((size_t)NB * sizeof(int));
    const size_t par_b = align256(((size_t)nb1 + 8) * sizeof(int));
    // union region U: build-time staging vs layer-time XW2+Ha
    const size_t stg_b  = align256((size_t)8 * E * sizeof(int2));       // 32 MB
    const size_t srl_b  = align256((size_t)8 * E);                      // 4 MB
    const size_t xw2_b  = align256((size_t)2 * N * OUTW * sizeof(__hip_bfloat16)); // 25.6 MB
    const size_t xw1_b  = align256((size_t)1 * N * OUTW * sizeof(__hip_bfloat16)); // 12.8 MB
    const size_t ha_b   = align256((size_t)2 * N * DOUT * sizeof(float));          // 25.6 MB

    const size_t fixed = cv_b + rp_b + cnt_b + bc_b + par_b;
    const size_t U_big = (stg_b + srl_b > xw2_b + ha_b) ? (stg_b + srl_b) : (xw2_b + ha_b);
    const int big = (ws_size >= fixed + U_big) ? 1 : 0;

    char* w = (char*)d_ws;
    int2* cv      = (int2*)w;  w += cv_b;
    int*  row_ptr = (int*)w;   w += rp_b;
    int*  cnt     = (int*)w;   w += cnt_b;   // histogram, then fallback cursor
    int*  bcur    = (int*)w;   w += bc_b;
    int*  partials= (int*)w;   w += par_b;
    char* U       = w;
    int2* stg = (int2*)U;
    unsigned char* srl = (unsigned char*)(U + stg_b);
    __hip_bfloat16* XW2 = (__hip_bfloat16*)U;
    float* Ha = (float*)(U + (big ? xw2_b : xw1_b));
    float* out = (float*)d_out;

    // ---- build CSR (segments 0..3 = adj1, 4..7 = adj2)
    const dim3 egrid((E + 255) / 256, 8);
    hipMemsetAsync(cnt, 0, (size_t)M * sizeof(int), stream);
    k_hist<<<egrid, 256, 0, stream>>>(adj1_rows, adj2_rows, E, N, cnt);
    k_scan1<<<nb1, 256, 0, stream>>>(cnt, M, row_ptr, partials);
    k_scan2<<<1, 256, 0, stream>>>(partials, nb1);
    k_scan3<<<nb1, 256, 0, stream>>>(row_ptr, cnt, partials, M, 8 * E);
    if (big) {
        k_binit<<<(NB + 255) / 256, 256, 0, stream>>>(row_ptr, bcur, N, NBper, NB);
        k_fillA<<<egrid, 256, 0, stream>>>(adj1_rows, adj1_cols, adj1_vals,
                                           adj2_rows, adj2_cols, adj2_vals,
                                           E, NBper, bcur, stg, srl);
        k_fillB<<<(NB + 3) / 4, 256, 0, stream>>>(stg, srl, row_ptr, N, NBper, NB, cv);
    } else {
        k_fill_direct<<<egrid, 256, 0, stream>>>(adj1_rows, adj1_cols, adj1_vals,
                                                 adj2_rows, adj2_cols, adj2_vals,
                                                 E, N, cnt, cv);
    }

    const dim3 ggrid_big((N + 15) / 16, 2), ggrid_small((N + 15) / 16, 1);
    const dim3 sgrid((N + 3) / 4, 2);

    auto layer = [&](const float* Hin, int d_in, int relu, const float* Wl,
                     int set4, float* Hout) {
        if (big) {
            if (relu) k_gemm<1><<<ggrid_big, 256, 0, stream>>>(Hin, Wl, XW2, N, d_in, 0);
            else      k_gemm<0><<<ggrid_big, 256, 0, stream>>>(Hin, Wl, XW2, N, d_in, 0);
            k_spmm<<<sgrid, 256, 0, stream>>>(row_ptr, set4, cv,
                                              (const unsigned short*)XW2, Hout, N, 1, 0, 0);
        } else {
            for (int j = 0; j < 2; ++j) {
                if (relu) k_gemm<1><<<ggrid_small, 256, 0, stream>>>(Hin, Wl, XW2, N, d_in, j);
                else      k_gemm<0><<<ggrid_small, 256, 0, stream>>>(Hin, Wl, XW2, N, d_in, j);
                k_spmm<<<sgrid, 256, 0, stream>>>(row_ptr, set4, cv,
                                                  (const unsigned short*)XW2, Hout, N, 0, j, j);
            }
        }
    };

    layer(feat, F,    0, W1, 0, Ha);   // L1: adj1
    layer(Ha,   DOUT, 1, W2, 0, out);  // L2: adj1
    layer(out,  DOUT, 1, W3, 4, Ha);   // L3: adj2
    layer(Ha,   DOUT, 1, W4, 4, out);  // L4: adj2 (final, no relu)
}

// Round 5
// 1316.245 us; speedup vs baseline: 1.3785x; 1.3785x over previous
//
#include <hip/hip_runtime.h>
#include <hip/hip_bf16.h>

// Multi-relational GCN, 4 layers. Round 5:
//  - REVERT to direct CSR fill (round-3 proven; bucketed fill was atomic-bound)
//  - quarter-wave SpMM: 16 lanes/edge, 4 edges per gather instruction
// relation r = 2*i + j: dst type i = r>>1, src type j = r&1.
// Segments 0..3 = adj1 (layers 1-2), 4..7 = adj2 (layers 3-4).

#define DOUT 64
#define OUTW 128

__device__ __forceinline__ float bf2f_lo(unsigned u) {
    return __uint_as_float(u << 16);
}
__device__ __forceinline__ float bf2f_hi(unsigned u) {
    return __uint_as_float(u & 0xffff0000u);
}

// ---------------- histogram of dst rows into cnt[s*N + row], s = 0..7
__global__ __launch_bounds__(256) void k_hist(
    const int* __restrict__ rows1, const int* __restrict__ rows2,
    int E, int N, int* __restrict__ cnt)
{
    const int s = blockIdx.y;
    const int* rows = (s < 4) ? rows1 : rows2;
    const int rl = s & 3;
    const int e = blockIdx.x * 256 + threadIdx.x;
    if (e < E) atomicAdd(&cnt[s * N + rows[(size_t)rl * E + e]], 1);
}

// ---------------- exclusive scan, 3-kernel
__global__ __launch_bounds__(256) void k_scan1(
    const int* __restrict__ cnt, int M, int* __restrict__ out, int* __restrict__ partials)
{
    __shared__ int sm[256];
    const int i = blockIdx.x * 256 + threadIdx.x;
    const int x = (i < M) ? cnt[i] : 0;
    sm[threadIdx.x] = x;
    __syncthreads();
    for (int off = 1; off < 256; off <<= 1) {
        int t = (threadIdx.x >= off) ? sm[threadIdx.x - off] : 0;
        __syncthreads();
        sm[threadIdx.x] += t;
        __syncthreads();
    }
    if (i < M) out[i] = sm[threadIdx.x] - x;
    if (threadIdx.x == 255) partials[blockIdx.x] = sm[255];
}

__global__ __launch_bounds__(256) void k_scan2(int* __restrict__ partials, int nb)
{
    __shared__ int sm[256];
    __shared__ int carry_s;
    if (threadIdx.x == 0) carry_s = 0;
    __syncthreads();
    for (int base = 0; base < nb; base += 256) {
        const int i = base + threadIdx.x;
        const int x = (i < nb) ? partials[i] : 0;
        sm[threadIdx.x] = x;
        __syncthreads();
        for (int off = 1; off < 256; off <<= 1) {
            int t = (threadIdx.x >= off) ? sm[threadIdx.x - off] : 0;
            __syncthreads();
            sm[threadIdx.x] += t;
            __syncthreads();
        }
        const int carry = carry_s;
        const int incl  = sm[threadIdx.x];
        __syncthreads();
        if (i < nb) partials[i] = incl - x + carry;
        if (threadIdx.x == 255) carry_s = carry + incl;
        __syncthreads();
    }
}

__global__ __launch_bounds__(256) void k_scan3(
    int* __restrict__ row_ptr, int* __restrict__ cursor,
    const int* __restrict__ partials, int M, int total)
{
    const int i = blockIdx.x * 256 + threadIdx.x;
    if (i < M) {
        const int v = row_ptr[i] + partials[blockIdx.x];
        row_ptr[i] = v;
        cursor[i]  = v;
    }
    if (i == 0) row_ptr[M] = total;
}

// ---------------- direct CSR fill (proven round-3 path)
__global__ __launch_bounds__(256) void k_fill_direct(
    const int* __restrict__ rows1, const int* __restrict__ cols1, const float* __restrict__ vals1,
    const int* __restrict__ rows2, const int* __restrict__ cols2, const float* __restrict__ vals2,
    int E, int N, int* __restrict__ cursor, int2* __restrict__ cv)
{
    const int s = blockIdx.y;
    const int e = blockIdx.x * 256 + threadIdx.x;
    if (e >= E) return;
    const int rl = s & 3;
    const int* rows = (s < 4) ? rows1 : rows2;
    const int* cols = (s < 4) ? cols1 : cols2;
    const float* vals = (s < 4) ? vals1 : vals2;
    const size_t idx = (size_t)rl * E + e;
    const int row = rows[idx];
    const int pos = atomicAdd(&cursor[s * N + row], 1);
    cv[pos] = make_int2(cols[idx], __float_as_int(vals[idx]));
}

// ---------------- dense transform: XW2[slice][n][0:64] = H_j W_j(dst0),
//                  [64:128] = H_j W_{2+j}(dst1);  bf16 output, register tiled.
template<int RELU>
__global__ __launch_bounds__(256) void k_gemm(
    const float* __restrict__ H,           // [2, N, d_in]
    const float* __restrict__ Wl,          // [4, d_in, 64]
    __hip_bfloat16* __restrict__ XW2,      // [nslice, N, 128]
    int N, int d_in, int joff)
{
    const int slice = blockIdx.y;
    const int j     = joff + slice;        // source node type
    const int col   = threadIdx.x & 63;
    const int half  = (threadIdx.x >> 6) & 1;
    const int rg    = threadIdx.x >> 7;
    const int row0  = blockIdx.x * 16 + rg * 8;

    const float* Hb = H  + (size_t)j * N * d_in;
    const float* Wb = Wl + (size_t)(half ? (2 + j) : j) * d_in * DOUT;

    int rowc[8];
#pragma unroll
    for (int m = 0; m < 8; ++m) {
        int row = row0 + m;
        rowc[m] = (row < N) ? row : (N - 1);
    }

    float acc[8];
#pragma unroll
    for (int m = 0; m < 8; ++m) acc[m] = 0.f;

#pragma unroll 2
    for (int k = 0; k < d_in; k += 4) {
        const float w0 = Wb[(k + 0) * DOUT + col];
        const float w1 = Wb[(k + 1) * DOUT + col];
        const float w2 = Wb[(k + 2) * DOUT + col];
        const float w3 = Wb[(k + 3) * DOUT + col];
#pragma unroll
        for (int m = 0; m < 8; ++m) {
            float4 h4 = *reinterpret_cast<const float4*>(Hb + (size_t)rowc[m] * d_in + k);
            if (RELU) {
                h4.x = fmaxf(h4.x, 0.f); h4.y = fmaxf(h4.y, 0.f);
                h4.z = fmaxf(h4.z, 0.f); h4.w = fmaxf(h4.w, 0.f);
            }
            acc[m] = fmaf(h4.x, w0, fmaf(h4.y, w1, fmaf(h4.z, w2, fmaf(h4.w, w3, acc[m]))));
        }
    }

#pragma unroll
    for (int m = 0; m < 8; ++m) {
        const int row = row0 + m;
        if (row < N)
            XW2[((size_t)slice * N + row) * OUTW + half * DOUT + col] =
                __float2bfloat16(acc[m]);
    }
}

// ---------------- quarter-wave CSR SpMM: 16 lanes per edge, 4 edges/instruction.
// One wave per dst row n; quarter qw handles edge t0+qw; lane ql covers cols
// [4*ql, 4*ql+3] (8B bf16x4 gather). Cross-quarter shfl_xor reduce at end.
__global__ __launch_bounds__(256) void k_spmm(
    const int* __restrict__ row_ptr, int set4,
    const int2* __restrict__ cv,
    const unsigned short* __restrict__ XW2,   // bf16 [nslice, N, 128]
    float* __restrict__ out,                  // [2, N, 64]
    int N, int two_src, int jsel, int beta)
{
    const int i    = blockIdx.y;
    const int n    = blockIdx.x * 4 + (threadIdx.x >> 6);
    const int lane = threadIdx.x & 63;
    const int qw   = lane >> 4;        // quarter 0..3 = edge slot
    const int ql   = lane & 15;        // lane within quarter = col group
    if (n >= N) return;

    float4 acc = make_float4(0.f, 0.f, 0.f, 0.f);

    const int nsrc = two_src ? 2 : 1;
    for (int js = 0; js < nsrc; ++js) {
        const int seg = set4 + 2 * i + (two_src ? js : jsel);
        const int* rp = row_ptr + (size_t)seg * N;
        const unsigned short* xw = XW2 + (two_src ? (size_t)js * N * OUTW : 0)
                                       + (size_t)i * DOUT + 4 * ql;
        const int s = rp[n];
        const int e = rp[n + 1];

        for (int t0 = s; t0 < e; t0 += 4) {
            const int t  = t0 + qw;
            const bool v = (t < e);
            const int tc = v ? t : (e - 1);            // e > s inside loop
            const int2 p = cv[tc];
            const float val = v ? __int_as_float(p.y) : 0.f;
            const uint2 u = *reinterpret_cast<const uint2*>(xw + ((size_t)p.x << 7));
            acc.x = fmaf(val, bf2f_lo(u.x), acc.x);
            acc.y = fmaf(val, bf2f_hi(u.x), acc.y);
            acc.z = fmaf(val, bf2f_lo(u.y), acc.z);
            acc.w = fmaf(val, bf2f_hi(u.y), acc.w);
        }
    }

    // reduce across the 4 quarters (lanes ql, ql+16, ql+32, ql+48)
#pragma unroll
    for (int m = 16; m < 64; m <<= 1) {
        acc.x += __shfl_xor(acc.x, m, 64);
        acc.y += __shfl_xor(acc.y, m, 64);
        acc.z += __shfl_xor(acc.z, m, 64);
        acc.w += __shfl_xor(acc.w, m, 64);
    }

    if (qw == 0) {
        float4* op = reinterpret_cast<float4*>(out + ((size_t)i * N + n) * DOUT + 4 * ql);
        if (beta) {
            const float4 o = *op;
            acc.x += o.x; acc.y += o.y; acc.z += o.z; acc.w += o.w;
        }
        *op = acc;
    }
}

extern "C" void kernel_launch(void* const* d_in, const int* in_sizes, int n_in,
                              void* d_out, int out_size, void* d_ws, size_t ws_size,
                              hipStream_t stream) {
    const float* feat      = (const float*)d_in[0];
    const int*   adj1_rows = (const int*)  d_in[1];
    const int*   adj1_cols = (const int*)  d_in[2];
    const float* adj1_vals = (const float*)d_in[3];
    const int*   adj2_rows = (const int*)  d_in[4];
    const int*   adj2_cols = (const int*)  d_in[5];
    const float* adj2_vals = (const float*)d_in[6];
    const float* W1        = (const float*)d_in[7];
    const float* W2        = (const float*)d_in[8];
    const float* W3        = (const float*)d_in[9];
    const float* W4        = (const float*)d_in[10];

    const int E = in_sizes[1] / 4;              // 500000
    const int F = in_sizes[7] / (4 * DOUT);     // 128
    const int N = in_sizes[0] / (2 * F);        // 50000
    const int M = 8 * N;
    const int nb1 = (M + 255) / 256;

    auto align256 = [](size_t x) { return (x + 255) & ~(size_t)255; };

    const size_t cv_b  = align256((size_t)8 * E * sizeof(int2));        // 32 MB
    const size_t rp_b  = align256(((size_t)M + 8) * sizeof(int));       // 1.6 MB
    const size_t cur_b = align256((size_t)M * sizeof(int));             // 1.6 MB
    const size_t par_b = align256(((size_t)nb1 + 8) * sizeof(int));
    const size_t xw2_b = align256((size_t)2 * N * OUTW * sizeof(__hip_bfloat16)); // 25.6 MB
    const size_t xw1_b = align256((size_t)1 * N * OUTW * sizeof(__hip_bfloat16)); // 12.8 MB
    const size_t ha_b  = align256((size_t)2 * N * DOUT * sizeof(float));          // 25.6 MB

    const int big = (ws_size >= cv_b + rp_b + cur_b + par_b + xw2_b + ha_b) ? 1 : 0;

    char* w = (char*)d_ws;
    int2* cv      = (int2*)w;  w += cv_b;
    int*  row_ptr = (int*)w;   w += rp_b;
    int*  cursor  = (int*)w;   w += cur_b;
    int*  partials= (int*)w;   w += par_b;
    __hip_bfloat16* XW2 = (__hip_bfloat16*)w;  w += big ? xw2_b : xw1_b;
    float* Ha = (float*)w;
    float* out = (float*)d_out;

    // ---- build CSR (segments 0..3 = adj1, 4..7 = adj2)
    const dim3 egrid((E + 255) / 256, 8);
    hipMemsetAsync(cursor, 0, (size_t)M * sizeof(int), stream);
    k_hist<<<egrid, 256, 0, stream>>>(adj1_rows, adj2_rows, E, N, cursor);
    k_scan1<<<nb1, 256, 0, stream>>>(cursor, M, row_ptr, partials);
    k_scan2<<<1, 256, 0, stream>>>(partials, nb1);
    k_scan3<<<nb1, 256, 0, stream>>>(row_ptr, cursor, partials, M, 8 * E);
    k_fill_direct<<<egrid, 256, 0, stream>>>(adj1_rows, adj1_cols, adj1_vals,
                                             adj2_rows, adj2_cols, adj2_vals,
                                             E, N, cursor, cv);

    const dim3 ggrid_big((N + 15) / 16, 2), ggrid_small((N + 15) / 16, 1);
    const dim3 sgrid((N + 3) / 4, 2);

    auto layer = [&](const float* Hin, int d_in, int relu, const float* Wl,
                     int set4, float* Hout) {
        if (big) {
            if (relu) k_gemm<1><<<ggrid_big, 256, 0, stream>>>(Hin, Wl, XW2, N, d_in, 0);
            else      k_gemm<0><<<ggrid_big, 256, 0, stream>>>(Hin, Wl, XW2, N, d_in, 0);
            k_spmm<<<sgrid, 256, 0, stream>>>(row_ptr, set4, cv,
                                              (const unsigned short*)XW2, Hout, N, 1, 0, 0);
        } else {
            for (int j = 0; j < 2; ++j) {
                if (relu) k_gemm<1><<<ggrid_small, 256, 0, stream>>>(Hin, Wl, XW2, N, d_in, j);
                else      k_gemm<0><<<ggrid_small, 256, 0, stream>>>(Hin, Wl, XW2, N, d_in, j);
                k_spmm<<<sgrid, 256, 0, stream>>>(row_ptr, set4, cv,
                                                  (const unsigned short*)XW2, Hout, N, 0, j, j);
            }
        }
    };

    layer(feat, F,    0, W1, 0, Ha);   // L1: adj1
    layer(Ha,   DOUT, 1, W2, 0, out);  // L2: adj1
    layer(out,  DOUT, 1, W3, 4, Ha);   // L3: adj2
    layer(Ha,   DOUT, 1, W4, 4, out);  // L4: adj2 (final, no relu)
}

// Round 6
// 1243.450 us; speedup vs baseline: 1.4592x; 1.0585x over previous
//
#include <hip/hip_runtime.h>
#include <hip/hip_bf16.h>

// Multi-relational GCN, 4 layers. Round 6:
//  - atomic-free CSR build: LDS-privatized histogram returns per-edge rank
//  - XCD-swizzled fill scatter (seg = bid&7 -> L2-local cv slice)
//  - L2-resident SpMM: XW[js][q][N][32] regions (3.2MB < per-XCD L2),
//    q = bid&3, 8 lanes/edge (8 edges per gather instr, 1 line/edge)
// relation r = 2*i + j: dst type i = r>>1, src type j = r&1.
// Segments 0..3 = adj1 (layers 1-2), 4..7 = adj2 (layers 3-4).

#define DOUT 64
#define WBINS 12800   // 51.2 KB LDS histogram window

__device__ __forceinline__ float bf2f_lo(unsigned u) {
    return __uint_as_float(u << 16);
}
__device__ __forceinline__ float bf2f_hi(unsigned u) {
    return __uint_as_float(u & 0xffff0000u);
}

// ---------------- build: LDS histogram + per-edge within-row rank (u16).
// grid (8 segments, nw windows), 1024 threads. One block owns (seg, window),
// so the LDS atomicAdd return value IS the edge's global within-row rank.
__global__ __launch_bounds__(1024) void k_build(
    const int* __restrict__ rows1, const int* __restrict__ rows2,
    int E, int N, int* __restrict__ cnt, unsigned short* __restrict__ rank)
{
    __shared__ int bins[WBINS];
    const int s  = blockIdx.x;
    const int w  = blockIdx.y;
    const int lo = w * WBINS;
    const int hi = min(N, lo + WBINS);
    const int nb = hi - lo;
    if (nb <= 0) return;
    const int* rows = (s < 4) ? rows1 : rows2;
    const size_t base = (size_t)(s & 3) * E;

    for (int b = threadIdx.x; b < nb; b += 1024) bins[b] = 0;
    __syncthreads();

    for (int e = threadIdx.x; e < E; e += 1024) {
        const int row = rows[base + e];
        if (row >= lo && row < hi) {
            const int r = atomicAdd(&bins[row - lo], 1);
            rank[(size_t)s * E + e] = (unsigned short)r;
        }
    }
    __syncthreads();

    for (int b = threadIdx.x; b < nb; b += 1024) cnt[(size_t)s * N + lo + b] = bins[b];
}

// ---------------- exclusive scan, 3-kernel
__global__ __launch_bounds__(256) void k_scan1(
    const int* __restrict__ cnt, int M, int* __restrict__ out, int* __restrict__ partials)
{
    __shared__ int sm[256];
    const int i = blockIdx.x * 256 + threadIdx.x;
    const int x = (i < M) ? cnt[i] : 0;
    sm[threadIdx.x] = x;
    __syncthreads();
    for (int off = 1; off < 256; off <<= 1) {
        int t = (threadIdx.x >= off) ? sm[threadIdx.x - off] : 0;
        __syncthreads();
        sm[threadIdx.x] += t;
        __syncthreads();
    }
    if (i < M) out[i] = sm[threadIdx.x] - x;
    if (threadIdx.x == 255) partials[blockIdx.x] = sm[255];
}

__global__ __launch_bounds__(256) void k_scan2(int* __restrict__ partials, int nb)
{
    __shared__ int sm[256];
    __shared__ int carry_s;
    if (threadIdx.x == 0) carry_s = 0;
    __syncthreads();
    for (int base = 0; base < nb; base += 256) {
        const int i = base + threadIdx.x;
        const int x = (i < nb) ? partials[i] : 0;
        sm[threadIdx.x] = x;
        __syncthreads();
        for (int off = 1; off < 256; off <<= 1) {
            int t = (threadIdx.x >= off) ? sm[threadIdx.x - off] : 0;
            __syncthreads();
            sm[threadIdx.x] += t;
            __syncthreads();
        }
        const int carry = carry_s;
        const int incl  = sm[threadIdx.x];
        __syncthreads();
        if (i < nb) partials[i] = incl - x + carry;
        if (threadIdx.x == 255) carry_s = carry + incl;
        __syncthreads();
    }
}

__global__ __launch_bounds__(256) void k_scan3(
    int* __restrict__ row_ptr, const int* __restrict__ partials, int M, int total)
{
    const int i = blockIdx.x * 256 + threadIdx.x;
    if (i < M) row_ptr[i] += partials[blockIdx.x];
    if (i == 0) row_ptr[M] = total;
}

// ---------------- atomic-free CSR fill; seg = bid&7 -> per-XCD cv slice
__global__ __launch_bounds__(256) void k_fill_nr(
    const int* __restrict__ rows1, const int* __restrict__ cols1, const float* __restrict__ vals1,
    const int* __restrict__ rows2, const int* __restrict__ cols2, const float* __restrict__ vals2,
    int E, int N, const int* __restrict__ row_ptr, const unsigned short* __restrict__ rank,
    int2* __restrict__ cv)
{
    const int bid = blockIdx.x;
    const int s   = bid & 7;
    const int e   = (bid >> 3) * 256 + threadIdx.x;
    if (e >= E) return;
    const int* rows   = (s < 4) ? rows1 : rows2;
    const int* cols   = (s < 4) ? cols1 : cols2;
    const float* vals = (s < 4) ? vals1 : vals2;
    const size_t idx  = (size_t)(s & 3) * E + e;
    const int row = rows[idx];
    const int pos = row_ptr[(size_t)s * N + row] + (int)rank[(size_t)s * E + e];
    cv[pos] = make_int2(cols[idx], __float_as_int(vals[idx]));
}

// ---------------- dense transform -> XWq[js][q][N][32] bf16, q = i*2 + (c>>5)
template<int RELU>
__global__ __launch_bounds__(256) void k_gemm(
    const float* __restrict__ H,           // [2, N, d_in]
    const float* __restrict__ Wl,          // [4, d_in, 64]
    __hip_bfloat16* __restrict__ XWq,      // [2][4][N][32]
    int N, int d_in)
{
    const int j     = blockIdx.y;          // source node type
    const int col   = threadIdx.x & 63;    // weight col 0..63
    const int half  = (threadIdx.x >> 6) & 1;  // dst type i (weight matrix)
    const int rg    = threadIdx.x >> 7;
    const int row0  = blockIdx.x * 16 + rg * 8;

    const float* Hb = H  + (size_t)j * N * d_in;
    const float* Wb = Wl + (size_t)(half ? (2 + j) : j) * d_in * DOUT;

    const int q   = half * 2 + (col >> 5);
    const int c32 = col & 31;
    __hip_bfloat16* xo = XWq + ((size_t)(j * 4 + q) * N) * 32 + c32;

    int rowc[8];
#pragma unroll
    for (int m = 0; m < 8; ++m) {
        int row = row0 + m;
        rowc[m] = (row < N) ? row : (N - 1);
    }

    float acc[8];
#pragma unroll
    for (int m = 0; m < 8; ++m) acc[m] = 0.f;

#pragma unroll 2
    for (int k = 0; k < d_in; k += 4) {
        const float w0 = Wb[(k + 0) * DOUT + col];
        const float w1 = Wb[(k + 1) * DOUT + col];
        const float w2 = Wb[(k + 2) * DOUT + col];
        const float w3 = Wb[(k + 3) * DOUT + col];
#pragma unroll
        for (int m = 0; m < 8; ++m) {
            float4 h4 = *reinterpret_cast<const float4*>(Hb + (size_t)rowc[m] * d_in + k);
            if (RELU) {
                h4.x = fmaxf(h4.x, 0.f); h4.y = fmaxf(h4.y, 0.f);
                h4.z = fmaxf(h4.z, 0.f); h4.w = fmaxf(h4.w, 0.f);
            }
            acc[m] = fmaf(h4.x, w0, fmaf(h4.y, w1, fmaf(h4.z, w2, fmaf(h4.w, w3, acc[m]))));
        }
    }

#pragma unroll
    for (int m = 0; m < 8; ++m) {
        const int row = row0 + m;
        if (row < N) xo[(size_t)row * 32] = __float2bfloat16(acc[m]);
    }
}

// ---------------- L2-resident SpMM: q = bid&3 (XCD-paired region), 8 lanes/edge.
// One wave per dst row per q; slot = lane>>3 picks edge, ol = lane&7 picks 4 cols.
template<int BETA>
__global__ __launch_bounds__(256) void k_spmmq(
    const int* __restrict__ row_ptr, int set4, int js,
    const int2* __restrict__ cv,
    const unsigned short* __restrict__ XWq,   // bf16 [2][4][N][32]
    float* __restrict__ out,                  // [2, N, 64]
    int N)
{
    const int bid    = blockIdx.x;
    const int q      = bid & 3;
    const int rowblk = bid >> 2;
    const int i  = q >> 1;
    const int ch = q & 1;
    const int wv = threadIdx.x >> 6;
    const int n  = rowblk * 4 + wv;
    if (n >= N) return;
    const int lane = threadIdx.x & 63;
    const int slot = lane >> 3;
    const int ol   = lane & 7;

    const int seg = set4 + 2 * i + js;
    const int* rp = row_ptr + (size_t)seg * N;
    const int s = rp[n];
    const int e = rp[n + 1];

    const unsigned short* xw = XWq + ((size_t)(js * 4 + q) * N) * 32 + 4 * ol;

    float4 acc = make_float4(0.f, 0.f, 0.f, 0.f);

    for (int t0 = s; t0 < e; t0 += 8) {
        const int t  = t0 + slot;
        const bool v = (t < e);
        const int tc = v ? t : (e - 1);
        const int2 p = cv[tc];
        const float val = v ? __int_as_float(p.y) : 0.f;
        const uint2 u = *reinterpret_cast<const uint2*>(xw + ((size_t)p.x << 5));
        acc.x = fmaf(val, bf2f_lo(u.x), acc.x);
        acc.y = fmaf(val, bf2f_hi(u.x), acc.y);
        acc.z = fmaf(val, bf2f_lo(u.y), acc.z);
        acc.w = fmaf(val, bf2f_hi(u.y), acc.w);
    }

#pragma unroll
    for (int m = 8; m < 64; m <<= 1) {
        acc.x += __shfl_xor(acc.x, m, 64);
        acc.y += __shfl_xor(acc.y, m, 64);
        acc.z += __shfl_xor(acc.z, m, 64);
        acc.w += __shfl_xor(acc.w, m, 64);
    }

    if (slot == 0) {
        float* op = out + ((size_t)i * N + n) * DOUT + ch * 32 + 4 * ol;
        if (BETA) {
            const float4 o = *reinterpret_cast<const float4*>(op);
            acc.x += o.x; acc.y += o.y; acc.z += o.z; acc.w += o.w;
        }
        *reinterpret_cast<float4*>(op) = acc;
    }
}

extern "C" void kernel_launch(void* const* d_in, const int* in_sizes, int n_in,
                              void* d_out, int out_size, void* d_ws, size_t ws_size,
                              hipStream_t stream) {
    const float* feat      = (const float*)d_in[0];
    const int*   adj1_rows = (const int*)  d_in[1];
    const int*   adj1_cols = (const int*)  d_in[2];
    const float* adj1_vals = (const float*)d_in[3];
    const int*   adj2_rows = (const int*)  d_in[4];
    const int*   adj2_cols = (const int*)  d_in[5];
    const float* adj2_vals = (const float*)d_in[6];
    const float* W1        = (const float*)d_in[7];
    const float* W2        = (const float*)d_in[8];
    const float* W3        = (const float*)d_in[9];
    const float* W4        = (const float*)d_in[10];

    const int E = in_sizes[1] / 4;              // 500000
    const int F = in_sizes[7] / (4 * DOUT);     // 128
    const int N = in_sizes[0] / (2 * F);        // 50000
    const int M = 8 * N;
    const int nb1 = (M + 255) / 256;
    const int nw  = (N + WBINS - 1) / WBINS;

    auto align256 = [](size_t x) { return (x + 255) & ~(size_t)255; };

    const size_t cv_b  = align256((size_t)8 * E * sizeof(int2));        // 32 MB
    const size_t rp_b  = align256(((size_t)M + 8) * sizeof(int));       // 1.6 MB
    const size_t cnt_b = align256((size_t)M * sizeof(int));             // 1.6 MB
    const size_t par_b = align256(((size_t)nb1 + 8) * sizeof(int));
    const size_t xw_b  = align256((size_t)8 * N * 32 * sizeof(__hip_bfloat16)); // 25.6 MB
    // Ha (25.6 MB) region also hosts rank (8 MB) during the build phase.

    char* w = (char*)d_ws;
    int2* cv      = (int2*)w;  w += cv_b;
    int*  row_ptr = (int*)w;   w += rp_b;
    int*  cnt     = (int*)w;   w += cnt_b;
    int*  partials= (int*)w;   w += par_b;
    __hip_bfloat16* XWq = (__hip_bfloat16*)w;  w += xw_b;
    float* Ha = (float*)w;
    unsigned short* rank = (unsigned short*)Ha;   // dead before Ha is written
    float* out = (float*)d_out;

    // ---- build CSR (segments 0..3 = adj1, 4..7 = adj2), no global atomics
    k_build<<<dim3(8, nw), 1024, 0, stream>>>(adj1_rows, adj2_rows, E, N, cnt, rank);
    k_scan1<<<nb1, 256, 0, stream>>>(cnt, M, row_ptr, partials);
    k_scan2<<<1, 256, 0, stream>>>(partials, nb1);
    k_scan3<<<nb1, 256, 0, stream>>>(row_ptr, partials, M, 8 * E);
    k_fill_nr<<<8 * ((E + 255) / 256), 256, 0, stream>>>(
        adj1_rows, adj1_cols, adj1_vals, adj2_rows, adj2_cols, adj2_vals,
        E, N, row_ptr, rank, cv);

    const dim3 ggrid((N + 15) / 16, 2);
    const int  sblocks = 4 * ((N + 3) / 4);

    auto layer = [&](const float* Hin, int d_in, int relu, const float* Wl,
                     int set4, float* Hout) {
        if (relu) k_gemm<1><<<ggrid, 256, 0, stream>>>(Hin, Wl, XWq, N, d_in);
        else      k_gemm<0><<<ggrid, 256, 0, stream>>>(Hin, Wl, XWq, N, d_in);
        k_spmmq<0><<<sblocks, 256, 0, stream>>>(row_ptr, set4, 0, cv,
                                                (const unsigned short*)XWq, Hout, N);
        k_spmmq<1><<<sblocks, 256, 0, stream>>>(row_ptr, set4, 1, cv,
                                                (const unsigned short*)XWq, Hout, N);
    };

    layer(feat, F,    0, W1, 0, Ha);   // L1: adj1
    layer(Ha,   DOUT, 1, W2, 0, out);  // L2: adj1
    layer(out,  DOUT, 1, W3, 4, Ha);   // L3: adj2
    layer(Ha,   DOUT, 1, W4, 4, out);  // L4: adj2 (final, no relu)
}

// Round 7
// 1189.712 us; speedup vs baseline: 1.5251x; 1.0452x over previous
//
#include <hip/hip_runtime.h>
#include <hip/hip_bf16.h>

// Multi-relational GCN, 4 layers. Round 7:
//  - chunked atomic-free CSR build: grid (window, seg, chunk) = 256 blocks,
//    LDS hist returns within-chunk rank (u16); k_rowsum prefixes chunk counts
//  - merged SpMM: one dispatch/layer, both relations accumulated in-register;
//    XW regions [js][8][N][16] bf16 (1.6MB; 2 per XCD = 3.2MB < 4MB L2)
// relation r = 2*i + j: dst type i = r>>1, src type j = r&1.
// Segments 0..3 = adj1 (layers 1-2), 4..7 = adj2 (layers 3-4).

#define DOUT 64
#define WBINS 12800   // 51.2 KB LDS histogram window
#define CCH   8       // edge chunks

__device__ __forceinline__ float bf2f_lo(unsigned u) {
    return __uint_as_float(u << 16);
}
__device__ __forceinline__ float bf2f_hi(unsigned u) {
    return __uint_as_float(u & 0xffff0000u);
}

// ---------------- build: per-(seg,window,chunk) LDS histogram + u16 rank
__global__ __launch_bounds__(1024) void k_build(
    const int* __restrict__ rows1, const int* __restrict__ rows2,
    int E, int chunkE, int N, int* __restrict__ cnt3, unsigned short* __restrict__ rank)
{
    __shared__ int bins[WBINS];
    const int w = blockIdx.x;
    const int s = blockIdx.y;
    const int c = blockIdx.z;
    const int lo = w * WBINS;
    const int hi = min(N, lo + WBINS);
    const int nb = hi - lo;
    if (nb <= 0) return;
    const int* rows = (s < 4) ? rows1 : rows2;
    const size_t base = (size_t)(s & 3) * E;
    const int e0 = c * chunkE;
    const int e1 = min(E, e0 + chunkE);

    for (int b = threadIdx.x; b < nb; b += 1024) bins[b] = 0;
    __syncthreads();

    for (int e = e0 + threadIdx.x; e < e1; e += 1024) {
        const int row = rows[base + e];
        if (row >= lo && row < hi) {
            const int r = atomicAdd(&bins[row - lo], 1);
            rank[(size_t)s * E + e] = (unsigned short)r;
        }
    }
    __syncthreads();

    for (int b = threadIdx.x; b < nb; b += 1024)
        cnt3[((size_t)(s * CCH + c)) * N + lo + b] = bins[b];
}

// ---------------- per-row: exclusive prefix over chunk counts (in place) + total
__global__ __launch_bounds__(256) void k_rowsum(
    int* __restrict__ cnt3, int* __restrict__ cnt, int N)
{
    const int row = blockIdx.x * 256 + threadIdx.x;
    const int s   = blockIdx.y;
    if (row >= N) return;
    int sum = 0;
#pragma unroll
    for (int c = 0; c < CCH; ++c) {
        const size_t idx = ((size_t)(s * CCH + c)) * N + row;
        const int v = cnt3[idx];
        cnt3[idx] = sum;
        sum += v;
    }
    cnt[(size_t)s * N + row] = sum;
}

// ---------------- exclusive scan, 3-kernel
__global__ __launch_bounds__(256) void k_scan1(
    const int* __restrict__ cnt, int M, int* __restrict__ out, int* __restrict__ partials)
{
    __shared__ int sm[256];
    const int i = blockIdx.x * 256 + threadIdx.x;
    const int x = (i < M) ? cnt[i] : 0;
    sm[threadIdx.x] = x;
    __syncthreads();
    for (int off = 1; off < 256; off <<= 1) {
        int t = (threadIdx.x >= off) ? sm[threadIdx.x - off] : 0;
        __syncthreads();
        sm[threadIdx.x] += t;
        __syncthreads();
    }
    if (i < M) out[i] = sm[threadIdx.x] - x;
    if (threadIdx.x == 255) partials[blockIdx.x] = sm[255];
}

__global__ __launch_bounds__(256) void k_scan2(int* __restrict__ partials, int nb)
{
    __shared__ int sm[256];
    __shared__ int carry_s;
    if (threadIdx.x == 0) carry_s = 0;
    __syncthreads();
    for (int base = 0; base < nb; base += 256) {
        const int i = base + threadIdx.x;
        const int x = (i < nb) ? partials[i] : 0;
        sm[threadIdx.x] = x;
        __syncthreads();
        for (int off = 1; off < 256; off <<= 1) {
            int t = (threadIdx.x >= off) ? sm[threadIdx.x - off] : 0;
            __syncthreads();
            sm[threadIdx.x] += t;
            __syncthreads();
        }
        const int carry = carry_s;
        const int incl  = sm[threadIdx.x];
        __syncthreads();
        if (i < nb) partials[i] = incl - x + carry;
        if (threadIdx.x == 255) carry_s = carry + incl;
        __syncthreads();
    }
}

__global__ __launch_bounds__(256) void k_scan3(
    int* __restrict__ row_ptr, const int* __restrict__ partials, int M, int total)
{
    const int i = blockIdx.x * 256 + threadIdx.x;
    if (i < M) row_ptr[i] += partials[blockIdx.x];
    if (i == 0) row_ptr[M] = total;
}

// ---------------- atomic-free CSR fill: pos = row_ptr + chunk_off + rank
__global__ __launch_bounds__(256) void k_fill(
    const int* __restrict__ rows1, const int* __restrict__ cols1, const float* __restrict__ vals1,
    const int* __restrict__ rows2, const int* __restrict__ cols2, const float* __restrict__ vals2,
    int E, int chunkE, int N, const int* __restrict__ row_ptr,
    const int* __restrict__ cnt3, const unsigned short* __restrict__ rank,
    int2* __restrict__ cv)
{
    const int s  = blockIdx.y;
    const int c  = blockIdx.z;
    const int el = blockIdx.x * 256 + threadIdx.x;
    const int e  = c * chunkE + el;
    if (el >= chunkE || e >= E) return;
    const int* rows   = (s < 4) ? rows1 : rows2;
    const int* cols   = (s < 4) ? cols1 : cols2;
    const float* vals = (s < 4) ? vals1 : vals2;
    const size_t idx  = (size_t)(s & 3) * E + e;
    const int row = rows[idx];
    const int pos = row_ptr[(size_t)s * N + row]
                  + cnt3[((size_t)(s * CCH + c)) * N + row]
                  + (int)rank[(size_t)s * E + e];
    cv[pos] = make_int2(cols[idx], __float_as_int(vals[idx]));
}

// ---------------- dense transform -> XWq[js][8][N][16] bf16
// region q' = i*4 + (col>>4); c16 = col&15
template<int RELU>
__global__ __launch_bounds__(256) void k_gemm(
    const float* __restrict__ H,           // [2, N, d_in]
    const float* __restrict__ Wl,          // [4, d_in, 64]
    __hip_bfloat16* __restrict__ XWq,      // [2][8][N][16]
    int N, int d_in)
{
    const int j     = blockIdx.y;          // source node type
    const int col   = threadIdx.x & 63;    // weight col 0..63
    const int half  = (threadIdx.x >> 6) & 1;  // dst type i
    const int rg    = threadIdx.x >> 7;
    const int row0  = blockIdx.x * 16 + rg * 8;

    const float* Hb = H  + (size_t)j * N * d_in;
    const float* Wb = Wl + (size_t)(half ? (2 + j) : j) * d_in * DOUT;

    const int q   = half * 4 + (col >> 4);
    const int c16 = col & 15;
    __hip_bfloat16* xo = XWq + ((size_t)(j * 8 + q) * N) * 16 + c16;

    int rowc[8];
#pragma unroll
    for (int m = 0; m < 8; ++m) {
        int row = row0 + m;
        rowc[m] = (row < N) ? row : (N - 1);
    }

    float acc[8];
#pragma unroll
    for (int m = 0; m < 8; ++m) acc[m] = 0.f;

#pragma unroll 2
    for (int k = 0; k < d_in; k += 4) {
        const float w0 = Wb[(k + 0) * DOUT + col];
        const float w1 = Wb[(k + 1) * DOUT + col];
        const float w2 = Wb[(k + 2) * DOUT + col];
        const float w3 = Wb[(k + 3) * DOUT + col];
#pragma unroll
        for (int m = 0; m < 8; ++m) {
            float4 h4 = *reinterpret_cast<const float4*>(Hb + (size_t)rowc[m] * d_in + k);
            if (RELU) {
                h4.x = fmaxf(h4.x, 0.f); h4.y = fmaxf(h4.y, 0.f);
                h4.z = fmaxf(h4.z, 0.f); h4.w = fmaxf(h4.w, 0.f);
            }
            acc[m] = fmaf(h4.x, w0, fmaf(h4.y, w1, fmaf(h4.z, w2, fmaf(h4.w, w3, acc[m]))));
        }
    }

#pragma unroll
    for (int m = 0; m < 8; ++m) {
        const int row = row0 + m;
        if (row < N) xo[(size_t)row * 16] = __float2bfloat16(acc[m]);
    }
}

// ---------------- merged SpMM: one wave per (dst row, 16-col region), both
// relations accumulated. q' = bid&7 -> XCD-local 1.6MB regions (js pair 3.2MB).
// slot = lane>>2 picks edge (16 edges/instr), ol = lane&3 picks 4 cols.
__global__ __launch_bounds__(256) void k_spmm(
    const int* __restrict__ row_ptr, int set4,
    const int2* __restrict__ cv,
    const unsigned short* __restrict__ XWq,   // bf16 [2][8][N][16]
    float* __restrict__ out,                  // [2, N, 64]
    int N)
{
    const int bid    = blockIdx.x;
    const int q      = bid & 7;
    const int rowblk = bid >> 3;
    const int i    = q >> 2;
    const int colq = q & 3;
    const int wv   = threadIdx.x >> 6;
    const int n    = rowblk * 4 + wv;
    if (n >= N) return;
    const int lane = threadIdx.x & 63;
    const int slot = lane >> 2;
    const int ol   = lane & 3;

    float4 acc = make_float4(0.f, 0.f, 0.f, 0.f);

#pragma unroll
    for (int js = 0; js < 2; ++js) {
        const int seg = set4 + 2 * i + js;
        const int* rp = row_ptr + (size_t)seg * N;
        const int s = rp[n];
        const int e = rp[n + 1];
        const unsigned short* xw = XWq + ((size_t)(js * 8 + q) * N) * 16 + 4 * ol;

        for (int t0 = s; t0 < e; t0 += 16) {
            const int t  = t0 + slot;
            const bool v = (t < e);
            const int tc = v ? t : (e - 1);
            const int2 p = cv[tc];
            const float val = v ? __int_as_float(p.y) : 0.f;
            const uint2 u = *reinterpret_cast<const uint2*>(xw + ((size_t)p.x << 4));
            acc.x = fmaf(val, bf2f_lo(u.x), acc.x);
            acc.y = fmaf(val, bf2f_hi(u.x), acc.y);
            acc.z = fmaf(val, bf2f_lo(u.y), acc.z);
            acc.w = fmaf(val, bf2f_hi(u.y), acc.w);
        }
    }

#pragma unroll
    for (int m = 4; m < 64; m <<= 1) {
        acc.x += __shfl_xor(acc.x, m, 64);
        acc.y += __shfl_xor(acc.y, m, 64);
        acc.z += __shfl_xor(acc.z, m, 64);
        acc.w += __shfl_xor(acc.w, m, 64);
    }

    if (slot == 0) {
        float* op = out + ((size_t)i * N + n) * DOUT + colq * 16 + 4 * ol;
        *reinterpret_cast<float4*>(op) = acc;
    }
}

extern "C" void kernel_launch(void* const* d_in, const int* in_sizes, int n_in,
                              void* d_out, int out_size, void* d_ws, size_t ws_size,
                              hipStream_t stream) {
    const float* feat      = (const float*)d_in[0];
    const int*   adj1_rows = (const int*)  d_in[1];
    const int*   adj1_cols = (const int*)  d_in[2];
    const float* adj1_vals = (const float*)d_in[3];
    const int*   adj2_rows = (const int*)  d_in[4];
    const int*   adj2_cols = (const int*)  d_in[5];
    const float* adj2_vals = (const float*)d_in[6];
    const float* W1        = (const float*)d_in[7];
    const float* W2        = (const float*)d_in[8];
    const float* W3        = (const float*)d_in[9];
    const float* W4        = (const float*)d_in[10];

    const int E = in_sizes[1] / 4;              // 500000
    const int F = in_sizes[7] / (4 * DOUT);     // 128
    const int N = in_sizes[0] / (2 * F);        // 50000
    const int M = 8 * N;
    const int nb1 = (M + 255) / 256;
    const int nw  = (N + WBINS - 1) / WBINS;
    const int chunkE = (E + CCH - 1) / CCH;

    auto align256 = [](size_t x) { return (x + 255) & ~(size_t)255; };

    const size_t cv_b   = align256((size_t)8 * E * sizeof(int2));        // 32 MB
    const size_t rp_b   = align256(((size_t)M + 8) * sizeof(int));       // 1.6 MB
    const size_t xwq_b  = align256((size_t)2 * 8 * N * 16 * sizeof(__hip_bfloat16)); // 25.6 MB
    // Ha region (25.6 MB) hosts rank (8 MB) + cnt (1.6 MB) + partials during build.
    // XWq region hosts cnt3 (12.8 MB) during build.

    char* w = (char*)d_ws;
    int2* cv      = (int2*)w;  w += cv_b;
    int*  row_ptr = (int*)w;   w += rp_b;
    __hip_bfloat16* XWq = (__hip_bfloat16*)w;
    int*  cnt3    = (int*)w;   w += xwq_b;
    float* Ha     = (float*)w;
    unsigned short* rank = (unsigned short*)Ha;
    int*  cnt     = (int*)((char*)Ha + align256((size_t)8 * E * sizeof(unsigned short)));
    int*  partials= (int*)((char*)cnt + align256((size_t)M * sizeof(int)));
    float* out    = (float*)d_out;

    // ---- build CSR (segments 0..3 = adj1, 4..7 = adj2), no global atomics
    k_build<<<dim3(nw, 8, CCH), 1024, 0, stream>>>(adj1_rows, adj2_rows, E, chunkE, N, cnt3, rank);
    k_rowsum<<<dim3((N + 255) / 256, 8), 256, 0, stream>>>(cnt3, cnt, N);
    k_scan1<<<nb1, 256, 0, stream>>>(cnt, M, row_ptr, partials);
    k_scan2<<<1, 256, 0, stream>>>(partials, nb1);
    k_scan3<<<nb1, 256, 0, stream>>>(row_ptr, partials, M, 8 * E);
    k_fill<<<dim3((chunkE + 255) / 256, 8, CCH), 256, 0, stream>>>(
        adj1_rows, adj1_cols, adj1_vals, adj2_rows, adj2_cols, adj2_vals,
        E, chunkE, N, row_ptr, cnt3, rank, cv);

    const dim3 ggrid((N + 15) / 16, 2);
    const int  sblocks = 8 * ((N + 3) / 4);

    auto layer = [&](const float* Hin, int d_in, int relu, const float* Wl,
                     int set4, float* Hout) {
        if (relu) k_gemm<1><<<ggrid, 256, 0, stream>>>(Hin, Wl, XWq, N, d_in);
        else      k_gemm<0><<<ggrid, 256, 0, stream>>>(Hin, Wl, XWq, N, d_in);
        k_spmm<<<sblocks, 256, 0, stream>>>(row_ptr, set4, cv,
                                            (const unsigned short*)XWq, Hout, N);
    };

    layer(feat, F,    0, W1, 0, Ha);   // L1: adj1
    layer(Ha,   DOUT, 1, W2, 0, out);  // L2: adj1
    layer(out,  DOUT, 1, W3, 4, Ha);   // L3: adj2
    layer(Ha,   DOUT, 1, W4, 4, out);  // L4: adj2 (final, no relu)
}

// Round 8
// 1159.608 us; speedup vs baseline: 1.5647x; 1.0260x over previous
//
#include <hip/hip_runtime.h>
#include <hip/hip_bf16.h>

// Multi-relational GCN, 4 layers. Round 8:
//  - gemm: LDS-repack epilogue -> fully-coalesced uint4 stores (was 2B scatter)
//  - ReLU moved from gemm input path to spmm output store (once per element)
//  - build/scan/fill/spmm as round 7 (chunked atomic-free CSR, merged spmm)
// relation r = 2*i + j: dst type i = r>>1, src type j = r&1.
// Segments 0..3 = adj1 (layers 1-2), 4..7 = adj2 (layers 3-4).

#define DOUT 64
#define WBINS 12800   // 51.2 KB LDS histogram window
#define CCH   8       // edge chunks

__device__ __forceinline__ float bf2f_lo(unsigned u) {
    return __uint_as_float(u << 16);
}
__device__ __forceinline__ float bf2f_hi(unsigned u) {
    return __uint_as_float(u & 0xffff0000u);
}

// ---------------- build: per-(seg,window,chunk) LDS histogram + u16 rank
__global__ __launch_bounds__(1024) void k_build(
    const int* __restrict__ rows1, const int* __restrict__ rows2,
    int E, int chunkE, int N, int* __restrict__ cnt3, unsigned short* __restrict__ rank)
{
    __shared__ int bins[WBINS];
    const int w = blockIdx.x;
    const int s = blockIdx.y;
    const int c = blockIdx.z;
    const int lo = w * WBINS;
    const int hi = min(N, lo + WBINS);
    const int nb = hi - lo;
    if (nb <= 0) return;
    const int* rows = (s < 4) ? rows1 : rows2;
    const size_t base = (size_t)(s & 3) * E;
    const int e0 = c * chunkE;
    const int e1 = min(E, e0 + chunkE);

    for (int b = threadIdx.x; b < nb; b += 1024) bins[b] = 0;
    __syncthreads();

    for (int e = e0 + threadIdx.x; e < e1; e += 1024) {
        const int row = rows[base + e];
        if (row >= lo && row < hi) {
            const int r = atomicAdd(&bins[row - lo], 1);
            rank[(size_t)s * E + e] = (unsigned short)r;
        }
    }
    __syncthreads();

    for (int b = threadIdx.x; b < nb; b += 1024)
        cnt3[((size_t)(s * CCH + c)) * N + lo + b] = bins[b];
}

// ---------------- per-row: exclusive prefix over chunk counts (in place) + total
__global__ __launch_bounds__(256) void k_rowsum(
    int* __restrict__ cnt3, int* __restrict__ cnt, int N)
{
    const int row = blockIdx.x * 256 + threadIdx.x;
    const int s   = blockIdx.y;
    if (row >= N) return;
    int sum = 0;
#pragma unroll
    for (int c = 0; c < CCH; ++c) {
        const size_t idx = ((size_t)(s * CCH + c)) * N + row;
        const int v = cnt3[idx];
        cnt3[idx] = sum;
        sum += v;
    }
    cnt[(size_t)s * N + row] = sum;
}

// ---------------- exclusive scan, 3-kernel
__global__ __launch_bounds__(256) void k_scan1(
    const int* __restrict__ cnt, int M, int* __restrict__ out, int* __restrict__ partials)
{
    __shared__ int sm[256];
    const int i = blockIdx.x * 256 + threadIdx.x;
    const int x = (i < M) ? cnt[i] : 0;
    sm[threadIdx.x] = x;
    __syncthreads();
    for (int off = 1; off < 256; off <<= 1) {
        int t = (threadIdx.x >= off) ? sm[threadIdx.x - off] : 0;
        __syncthreads();
        sm[threadIdx.x] += t;
        __syncthreads();
    }
    if (i < M) out[i] = sm[threadIdx.x] - x;
    if (threadIdx.x == 255) partials[blockIdx.x] = sm[255];
}

__global__ __launch_bounds__(256) void k_scan2(int* __restrict__ partials, int nb)
{
    __shared__ int sm[256];
    __shared__ int carry_s;
    if (threadIdx.x == 0) carry_s = 0;
    __syncthreads();
    for (int base = 0; base < nb; base += 256) {
        const int i = base + threadIdx.x;
        const int x = (i < nb) ? partials[i] : 0;
        sm[threadIdx.x] = x;
        __syncthreads();
        for (int off = 1; off < 256; off <<= 1) {
            int t = (threadIdx.x >= off) ? sm[threadIdx.x - off] : 0;
            __syncthreads();
            sm[threadIdx.x] += t;
            __syncthreads();
        }
        const int carry = carry_s;
        const int incl  = sm[threadIdx.x];
        __syncthreads();
        if (i < nb) partials[i] = incl - x + carry;
        if (threadIdx.x == 255) carry_s = carry + incl;
        __syncthreads();
    }
}

__global__ __launch_bounds__(256) void k_scan3(
    int* __restrict__ row_ptr, const int* __restrict__ partials, int M, int total)
{
    const int i = blockIdx.x * 256 + threadIdx.x;
    if (i < M) row_ptr[i] += partials[blockIdx.x];
    if (i == 0) row_ptr[M] = total;
}

// ---------------- atomic-free CSR fill: pos = row_ptr + chunk_off + rank
__global__ __launch_bounds__(256) void k_fill(
    const int* __restrict__ rows1, const int* __restrict__ cols1, const float* __restrict__ vals1,
    const int* __restrict__ rows2, const int* __restrict__ cols2, const float* __restrict__ vals2,
    int E, int chunkE, int N, const int* __restrict__ row_ptr,
    const int* __restrict__ cnt3, const unsigned short* __restrict__ rank,
    int2* __restrict__ cv)
{
    const int s  = blockIdx.y;
    const int c  = blockIdx.z;
    const int el = blockIdx.x * 256 + threadIdx.x;
    const int e  = c * chunkE + el;
    if (el >= chunkE || e >= E) return;
    const int* rows   = (s < 4) ? rows1 : rows2;
    const int* cols   = (s < 4) ? cols1 : cols2;
    const float* vals = (s < 4) ? vals1 : vals2;
    const size_t idx  = (size_t)(s & 3) * E + e;
    const int row = rows[idx];
    const int pos = row_ptr[(size_t)s * N + row]
                  + cnt3[((size_t)(s * CCH + c)) * N + row]
                  + (int)rank[(size_t)s * E + e];
    cv[pos] = make_int2(cols[idx], __float_as_int(vals[idx]));
}

// ---------------- dense transform -> XWq[j][8][N][16] bf16, q = half*4 + (c>>4)
// Accumulate as before (broadcast-friendly loads), then LDS-repack the block's
// 16x128 tile so each thread emits ONE fully-coalesced uint4 store.
__global__ __launch_bounds__(256) void k_gemm(
    const float* __restrict__ H,           // [2, N, d_in]
    const float* __restrict__ Wl,          // [4, d_in, 64]
    __hip_bfloat16* __restrict__ XWq,      // [2][8][N][16]
    int N, int d_in)
{
    __shared__ __hip_bfloat16 lds_o[16][136];   // 128 cols + pad 8 (16B-align rows)

    const int j     = blockIdx.y;          // source node type
    const int col   = threadIdx.x & 63;    // weight col 0..63
    const int half  = (threadIdx.x >> 6) & 1;  // dst type i
    const int rg    = threadIdx.x >> 7;
    const int row0  = blockIdx.x * 16 + rg * 8;

    const float* Hb = H  + (size_t)j * N * d_in;
    const float* Wb = Wl + (size_t)(half ? (2 + j) : j) * d_in * DOUT;

    int rowc[8];
#pragma unroll
    for (int m = 0; m < 8; ++m) {
        int row = row0 + m;
        rowc[m] = (row < N) ? row : (N - 1);
    }

    float acc[8];
#pragma unroll
    for (int m = 0; m < 8; ++m) acc[m] = 0.f;

#pragma unroll 4
    for (int k = 0; k < d_in; k += 4) {
        const float w0 = Wb[(k + 0) * DOUT + col];
        const float w1 = Wb[(k + 1) * DOUT + col];
        const float w2 = Wb[(k + 2) * DOUT + col];
        const float w3 = Wb[(k + 3) * DOUT + col];
#pragma unroll
        for (int m = 0; m < 8; ++m) {
            float4 h4 = *reinterpret_cast<const float4*>(Hb + (size_t)rowc[m] * d_in + k);
            acc[m] = fmaf(h4.x, w0, fmaf(h4.y, w1, fmaf(h4.z, w2, fmaf(h4.w, w3, acc[m]))));
        }
    }

    // stage tile in LDS (2-way write aliasing = free)
#pragma unroll
    for (int m = 0; m < 8; ++m)
        lds_o[rg * 8 + m][half * 64 + col] = __float2bfloat16(acc[m]);
    __syncthreads();

    // repack: thread t -> region q = t>>5, tile row r16 = (t>>1)&15, half-row hh = t&1
    const int t   = threadIdx.x;
    const int q   = t >> 5;
    const int r16 = (t >> 1) & 15;
    const int hh  = t & 1;
    const int drow = blockIdx.x * 16 + r16;
    if (drow < N) {
        const uint4 v = *reinterpret_cast<const uint4*>(
            &lds_o[r16][(q >> 2) * 64 + (q & 3) * 16 + hh * 8]);
        *reinterpret_cast<uint4*>(
            XWq + ((size_t)(j * 8 + q) * N + drow) * 16 + hh * 8) = v;
    }
}

// ---------------- merged SpMM: one wave per (dst row, 16-col region), both
// relations accumulated. q = bid&7 -> XCD-local 1.6MB regions (js pair 3.2MB).
// slot = lane>>2 picks edge (16 edges/instr), ol = lane&3 picks 4 cols.
// RELU applies the next layer's input activation at store time.
template<int RELU>
__global__ __launch_bounds__(256) void k_spmm(
    const int* __restrict__ row_ptr, int set4,
    const int2* __restrict__ cv,
    const unsigned short* __restrict__ XWq,   // bf16 [2][8][N][16]
    float* __restrict__ out,                  // [2, N, 64]
    int N)
{
    const int bid    = blockIdx.x;
    const int q      = bid & 7;
    const int rowblk = bid >> 3;
    const int i    = q >> 2;
    const int colq = q & 3;
    const int wv   = threadIdx.x >> 6;
    const int n    = rowblk * 4 + wv;
    if (n >= N) return;
    const int lane = threadIdx.x & 63;
    const int slot = lane >> 2;
    const int ol   = lane & 3;

    float4 acc = make_float4(0.f, 0.f, 0.f, 0.f);

#pragma unroll
    for (int js = 0; js < 2; ++js) {
        const int seg = set4 + 2 * i + js;
        const int* rp = row_ptr + (size_t)seg * N;
        const int s = rp[n];
        const int e = rp[n + 1];
        const unsigned short* xw = XWq + ((size_t)(js * 8 + q) * N) * 16 + 4 * ol;

        for (int t0 = s; t0 < e; t0 += 16) {
            const int t  = t0 + slot;
            const bool v = (t < e);
            const int tc = v ? t : (e - 1);
            const int2 p = cv[tc];
            const float val = v ? __int_as_float(p.y) : 0.f;
            const uint2 u = *reinterpret_cast<const uint2*>(xw + ((size_t)p.x << 4));
            acc.x = fmaf(val, bf2f_lo(u.x), acc.x);
            acc.y = fmaf(val, bf2f_hi(u.x), acc.y);
            acc.z = fmaf(val, bf2f_lo(u.y), acc.z);
            acc.w = fmaf(val, bf2f_hi(u.y), acc.w);
        }
    }

#pragma unroll
    for (int m = 4; m < 64; m <<= 1) {
        acc.x += __shfl_xor(acc.x, m, 64);
        acc.y += __shfl_xor(acc.y, m, 64);
        acc.z += __shfl_xor(acc.z, m, 64);
        acc.w += __shfl_xor(acc.w, m, 64);
    }

    if (slot == 0) {
        if (RELU) {
            acc.x = fmaxf(acc.x, 0.f); acc.y = fmaxf(acc.y, 0.f);
            acc.z = fmaxf(acc.z, 0.f); acc.w = fmaxf(acc.w, 0.f);
        }
        float* op = out + ((size_t)i * N + n) * DOUT + colq * 16 + 4 * ol;
        *reinterpret_cast<float4*>(op) = acc;
    }
}

extern "C" void kernel_launch(void* const* d_in, const int* in_sizes, int n_in,
                              void* d_out, int out_size, void* d_ws, size_t ws_size,
                              hipStream_t stream) {
    const float* feat      = (const float*)d_in[0];
    const int*   adj1_rows = (const int*)  d_in[1];
    const int*   adj1_cols = (const int*)  d_in[2];
    const float* adj1_vals = (const float*)d_in[3];
    const int*   adj2_rows = (const int*)  d_in[4];
    const int*   adj2_cols = (const int*)  d_in[5];
    const float* adj2_vals = (const float*)d_in[6];
    const float* W1        = (const float*)d_in[7];
    const float* W2        = (const float*)d_in[8];
    const float* W3        = (const float*)d_in[9];
    const float* W4        = (const float*)d_in[10];

    const int E = in_sizes[1] / 4;              // 500000
    const int F = in_sizes[7] / (4 * DOUT);     // 128
    const int N = in_sizes[0] / (2 * F);        // 50000
    const int M = 8 * N;
    const int nb1 = (M + 255) / 256;
    const int nw  = (N + WBINS - 1) / WBINS;
    const int chunkE = (E + CCH - 1) / CCH;

    auto align256 = [](size_t x) { return (x + 255) & ~(size_t)255; };

    const size_t cv_b   = align256((size_t)8 * E * sizeof(int2));        // 32 MB
    const size_t rp_b   = align256(((size_t)M + 8) * sizeof(int));       // 1.6 MB
    const size_t xwq_b  = align256((size_t)2 * 8 * N * 16 * sizeof(__hip_bfloat16)); // 25.6 MB
    // Ha region (25.6 MB) hosts rank (8 MB) + cnt (1.6 MB) + partials during build.
    // XWq region hosts cnt3 (12.8 MB) during build.

    char* w = (char*)d_ws;
    int2* cv      = (int2*)w;  w += cv_b;
    int*  row_ptr = (int*)w;   w += rp_b;
    __hip_bfloat16* XWq = (__hip_bfloat16*)w;
    int*  cnt3    = (int*)w;   w += xwq_b;
    float* Ha     = (float*)w;
    unsigned short* rank = (unsigned short*)Ha;
    int*  cnt     = (int*)((char*)Ha + align256((size_t)8 * E * sizeof(unsigned short)));
    int*  partials= (int*)((char*)cnt + align256((size_t)M * sizeof(int)));
    float* out    = (float*)d_out;

    // ---- build CSR (segments 0..3 = adj1, 4..7 = adj2), no global atomics
    k_build<<<dim3(nw, 8, CCH), 1024, 0, stream>>>(adj1_rows, adj2_rows, E, chunkE, N, cnt3, rank);
    k_rowsum<<<dim3((N + 255) / 256, 8), 256, 0, stream>>>(cnt3, cnt, N);
    k_scan1<<<nb1, 256, 0, stream>>>(cnt, M, row_ptr, partials);
    k_scan2<<<1, 256, 0, stream>>>(partials, nb1);
    k_scan3<<<nb1, 256, 0, stream>>>(row_ptr, partials, M, 8 * E);
    k_fill<<<dim3((chunkE + 255) / 256, 8, CCH), 256, 0, stream>>>(
        adj1_rows, adj1_cols, adj1_vals, adj2_rows, adj2_cols, adj2_vals,
        E, chunkE, N, row_ptr, cnt3, rank, cv);

    const dim3 ggrid((N + 15) / 16, 2);
    const int  sblocks = 8 * ((N + 3) / 4);

    auto layer = [&](const float* Hin, int d_in, const float* Wl,
                     int set4, float* Hout, int relu_out) {
        k_gemm<<<ggrid, 256, 0, stream>>>(Hin, Wl, XWq, N, d_in);
        if (relu_out)
            k_spmm<1><<<sblocks, 256, 0, stream>>>(row_ptr, set4, cv,
                                                   (const unsigned short*)XWq, Hout, N);
        else
            k_spmm<0><<<sblocks, 256, 0, stream>>>(row_ptr, set4, cv,
                                                   (const unsigned short*)XWq, Hout, N);
    };

    layer(feat, F,    W1, 0, Ha,  1);   // L1: adj1, relu into L2 input
    layer(Ha,   DOUT, W2, 0, out, 1);   // L2: adj1, relu into L3 input
    layer(out,  DOUT, W3, 4, Ha,  1);   // L3: adj2, relu into L4 input
    layer(Ha,   DOUT, W4, 4, out, 0);   // L4: adj2 (final, no relu)
}

// Round 9
// 715.474 us; speedup vs baseline: 2.5361x; 1.6208x over previous
//
#include <hip/hip_runtime.h>
#include <hip/hip_bf16.h>

// Multi-relational GCN, 4 layers. Round 9:
//  - MFMA dense transform: W pre-packed to bf16 B-fragments (k_wprep, once),
//    A-fragments loaded per-lane from global (16 lines in flight), 16x16x32 bf16
//    MFMA, LDS-repack epilogue -> coalesced uint4 stores (r8 layout unchanged)
//  - build/scan/fill/spmm byte-identical to round 8
// relation r = 2*i + j: dst type i = r>>1, src type j = r&1.
// Segments 0..3 = adj1 (layers 1-2), 4..7 = adj2 (layers 3-4).

#define DOUT 64
#define WBINS 12800   // 51.2 KB LDS histogram window
#define CCH   8       // edge chunks

typedef __attribute__((ext_vector_type(8))) short s16x8;
typedef __attribute__((ext_vector_type(4))) float f32x4;

__device__ __forceinline__ float bf2f_lo(unsigned u) {
    return __uint_as_float(u << 16);
}
__device__ __forceinline__ float bf2f_hi(unsigned u) {
    return __uint_as_float(u & 0xffff0000u);
}
__device__ __forceinline__ short f2bf(float x) {
    union { __hip_bfloat16 h; short s; } u;
    u.h = __float2bfloat16(x);
    return u.s;
}

// ---------------- build: per-(seg,window,chunk) LDS histogram + u16 rank
__global__ __launch_bounds__(1024) void k_build(
    const int* __restrict__ rows1, const int* __restrict__ rows2,
    int E, int chunkE, int N, int* __restrict__ cnt3, unsigned short* __restrict__ rank)
{
    __shared__ int bins[WBINS];
    const int w = blockIdx.x;
    const int s = blockIdx.y;
    const int c = blockIdx.z;
    const int lo = w * WBINS;
    const int hi = min(N, lo + WBINS);
    const int nb = hi - lo;
    if (nb <= 0) return;
    const int* rows = (s < 4) ? rows1 : rows2;
    const size_t base = (size_t)(s & 3) * E;
    const int e0 = c * chunkE;
    const int e1 = min(E, e0 + chunkE);

    for (int b = threadIdx.x; b < nb; b += 1024) bins[b] = 0;
    __syncthreads();

    for (int e = e0 + threadIdx.x; e < e1; e += 1024) {
        const int row = rows[base + e];
        if (row >= lo && row < hi) {
            const int r = atomicAdd(&bins[row - lo], 1);
            rank[(size_t)s * E + e] = (unsigned short)r;
        }
    }
    __syncthreads();

    for (int b = threadIdx.x; b < nb; b += 1024)
        cnt3[((size_t)(s * CCH + c)) * N + lo + b] = bins[b];
}

// ---------------- per-row: exclusive prefix over chunk counts (in place) + total
__global__ __launch_bounds__(256) void k_rowsum(
    int* __restrict__ cnt3, int* __restrict__ cnt, int N)
{
    const int row = blockIdx.x * 256 + threadIdx.x;
    const int s   = blockIdx.y;
    if (row >= N) return;
    int sum = 0;
#pragma unroll
    for (int c = 0; c < CCH; ++c) {
        const size_t idx = ((size_t)(s * CCH + c)) * N + row;
        const int v = cnt3[idx];
        cnt3[idx] = sum;
        sum += v;
    }
    cnt[(size_t)s * N + row] = sum;
}

// ---------------- exclusive scan, 3-kernel
__global__ __launch_bounds__(256) void k_scan1(
    const int* __restrict__ cnt, int M, int* __restrict__ out, int* __restrict__ partials)
{
    __shared__ int sm[256];
    const int i = blockIdx.x * 256 + threadIdx.x;
    const int x = (i < M) ? cnt[i] : 0;
    sm[threadIdx.x] = x;
    __syncthreads();
    for (int off = 1; off < 256; off <<= 1) {
        int t = (threadIdx.x >= off) ? sm[threadIdx.x - off] : 0;
        __syncthreads();
        sm[threadIdx.x] += t;
        __syncthreads();
    }
    if (i < M) out[i] = sm[threadIdx.x] - x;
    if (threadIdx.x == 255) partials[blockIdx.x] = sm[255];
}

__global__ __launch_bounds__(256) void k_scan2(int* __restrict__ partials, int nb)
{
    __shared__ int sm[256];
    __shared__ int carry_s;
    if (threadIdx.x == 0) carry_s = 0;
    __syncthreads();
    for (int base = 0; base < nb; base += 256) {
        const int i = base + threadIdx.x;
        const int x = (i < nb) ? partials[i] : 0;
        sm[threadIdx.x] = x;
        __syncthreads();
        for (int off = 1; off < 256; off <<= 1) {
            int t = (threadIdx.x >= off) ? sm[threadIdx.x - off] : 0;
            __syncthreads();
            sm[threadIdx.x] += t;
            __syncthreads();
        }
        const int carry = carry_s;
        const int incl  = sm[threadIdx.x];
        __syncthreads();
        if (i < nb) partials[i] = incl - x + carry;
        if (threadIdx.x == 255) carry_s = carry + incl;
        __syncthreads();
    }
}

__global__ __launch_bounds__(256) void k_scan3(
    int* __restrict__ row_ptr, const int* __restrict__ partials, int M, int total)
{
    const int i = blockIdx.x * 256 + threadIdx.x;
    if (i < M) row_ptr[i] += partials[blockIdx.x];
    if (i == 0) row_ptr[M] = total;
}

// ---------------- atomic-free CSR fill: pos = row_ptr + chunk_off + rank
__global__ __launch_bounds__(256) void k_fill(
    const int* __restrict__ rows1, const int* __restrict__ cols1, const float* __restrict__ vals1,
    const int* __restrict__ rows2, const int* __restrict__ cols2, const float* __restrict__ vals2,
    int E, int chunkE, int N, const int* __restrict__ row_ptr,
    const int* __restrict__ cnt3, const unsigned short* __restrict__ rank,
    int2* __restrict__ cv)
{
    const int s  = blockIdx.y;
    const int c  = blockIdx.z;
    const int el = blockIdx.x * 256 + threadIdx.x;
    const int e  = c * chunkE + el;
    if (el >= chunkE || e >= E) return;
    const int* rows   = (s < 4) ? rows1 : rows2;
    const int* cols   = (s < 4) ? cols1 : cols2;
    const float* vals = (s < 4) ? vals1 : vals2;
    const size_t idx  = (size_t)(s & 3) * E + e;
    const int row = rows[idx];
    const int pos = row_ptr[(size_t)s * N + row]
                  + cnt3[((size_t)(s * CCH + c)) * N + row]
                  + (int)rank[(size_t)s * E + e];
    cv[pos] = make_int2(cols[idx], __float_as_int(vals[idx]));
}

// ---------------- W prep: bf16 B-fragments, layout [j][nt][ks][lane][8]
// nt = output 16-col tile (0..7): cols 0-63 = W[j] (dst 0), 64-127 = W[2+j].
__global__ __launch_bounds__(256) void k_wprep(
    const float* __restrict__ W, short* __restrict__ wb, int d_in)
{
    const int KS  = d_in >> 5;
    const int tid = blockIdx.x * 256 + threadIdx.x;
    if (tid >= 2 * 8 * KS * 64) return;
    const int l    = tid & 63;
    const int rest = tid >> 6;
    const int ks   = rest % KS;
    const int tt   = rest / KS;
    const int t    = tt & 7;
    const int j    = tt >> 3;
    const int r    = ((t >> 2) << 1) + j;            // t<4 -> j, t>=4 -> 2+j
    const int c    = ((t & 3) << 4) + (l & 15);      // col within the 64-wide W
    const int k0   = (ks << 5) + ((l >> 4) << 3);
    s16x8 v;
#pragma unroll
    for (int e = 0; e < 8; ++e)
        v[e] = f2bf(W[((size_t)r * d_in + k0 + e) * 64 + c]);
    *reinterpret_cast<s16x8*>(wb + (size_t)tid * 8) = v;
}

// ---------------- MFMA dense transform -> XWq[j][8][N][16] bf16
// Block: 64 rows x 128 cols, 4 waves x 16 rows. A per-lane from global (fp32
// -> bf16 in reg), B from prepped wb (L2). Epilogue: LDS repack -> uint4 stores.
template<int KS>
__global__ __launch_bounds__(256) void k_gemm(
    const float* __restrict__ H,           // [2, N, d_in]
    const short* __restrict__ wb,          // [2][8][KS][64][8] bf16 bits
    __hip_bfloat16* __restrict__ XWq,      // [2][8][N][16]
    int N)
{
    __shared__ __hip_bfloat16 lds_o[64][136];
    const int d_in = KS * 32;
    const int j    = blockIdx.y;
    const int wv   = threadIdx.x >> 6;
    const int lane = threadIdx.x & 63;
    const int row0 = blockIdx.x * 64;

    const int arow = row0 + wv * 16 + (lane & 15);
    const int rc   = (arow < N) ? arow : (N - 1);
    const float* Hb = H + (size_t)j * N * d_in + (size_t)rc * d_in + ((lane >> 4) << 3);

    // A fragments: lane holds row (lane&15), k = (lane>>4)*8 + e  (per ks)
    s16x8 a[KS];
#pragma unroll
    for (int ks = 0; ks < KS; ++ks) {
        union { float4 v; float f[4]; } f0, f1;
        f0.v = *reinterpret_cast<const float4*>(Hb + ks * 32);
        f1.v = *reinterpret_cast<const float4*>(Hb + ks * 32 + 4);
        s16x8 t;
#pragma unroll
        for (int e = 0; e < 4; ++e) { t[e] = f2bf(f0.f[e]); t[4 + e] = f2bf(f1.f[e]); }
        a[ks] = t;
    }

    f32x4 acc[8];
#pragma unroll
    for (int nt = 0; nt < 8; ++nt) acc[nt] = (f32x4){0.f, 0.f, 0.f, 0.f};

    const short* wbase = wb + ((size_t)j * 8 * KS * 64 + lane) * 8;
#pragma unroll
    for (int ks = 0; ks < KS; ++ks) {
#pragma unroll
        for (int nt = 0; nt < 8; ++nt) {
            const s16x8 b = *reinterpret_cast<const s16x8*>(
                wbase + (size_t)(nt * KS + ks) * 64 * 8);
            acc[nt] = __builtin_amdgcn_mfma_f32_16x16x32_bf16(a[ks], b, acc[nt], 0, 0, 0);
        }
    }

    // C/D layout: col = lane&15, row = (lane>>4)*4 + r
#pragma unroll
    for (int nt = 0; nt < 8; ++nt)
#pragma unroll
        for (int r = 0; r < 4; ++r)
            lds_o[wv * 16 + ((lane >> 4) << 2) + r][nt * 16 + (lane & 15)] =
                __float2bfloat16(acc[nt][r]);
    __syncthreads();

    const int t = threadIdx.x;
#pragma unroll
    for (int p = 0; p < 4; ++p) {
        const int r = p * 16 + (t >> 4);
        const int n = row0 + r;
        if (n < N) {
            const int g = t & 15;                      // 16B group: cols g*8..g*8+7
            const uint4 v = *reinterpret_cast<const uint4*>(&lds_o[r][g * 8]);
            *reinterpret_cast<uint4*>(
                (unsigned short*)XWq + ((size_t)(j * 8 + (g >> 1)) * N + n) * 16 + (g & 1) * 8) = v;
        }
    }
}

// ---------------- merged SpMM: one wave per (dst row, 16-col region), both
// relations accumulated. q = bid&7 -> XCD-local 1.6MB regions (js pair 3.2MB).
// slot = lane>>2 picks edge (16 edges/instr), ol = lane&3 picks 4 cols.
// RELU applies the next layer's input activation at store time.
template<int RELU>
__global__ __launch_bounds__(256) void k_spmm(
    const int* __restrict__ row_ptr, int set4,
    const int2* __restrict__ cv,
    const unsigned short* __restrict__ XWq,   // bf16 [2][8][N][16]
    float* __restrict__ out,                  // [2, N, 64]
    int N)
{
    const int bid    = blockIdx.x;
    const int q      = bid & 7;
    const int rowblk = bid >> 3;
    const int i    = q >> 2;
    const int colq = q & 3;
    const int wv   = threadIdx.x >> 6;
    const int n    = rowblk * 4 + wv;
    if (n >= N) return;
    const int lane = threadIdx.x & 63;
    const int slot = lane >> 2;
    const int ol   = lane & 3;

    float4 acc = make_float4(0.f, 0.f, 0.f, 0.f);

#pragma unroll
    for (int js = 0; js < 2; ++js) {
        const int seg = set4 + 2 * i + js;
        const int* rp = row_ptr + (size_t)seg * N;
        const int s = rp[n];
        const int e = rp[n + 1];
        const unsigned short* xw = XWq + ((size_t)(js * 8 + q) * N) * 16 + 4 * ol;

        for (int t0 = s; t0 < e; t0 += 16) {
            const int t  = t0 + slot;
            const bool v = (t < e);
            const int tc = v ? t : (e - 1);
            const int2 p = cv[tc];
            const float val = v ? __int_as_float(p.y) : 0.f;
            const uint2 u = *reinterpret_cast<const uint2*>(xw + ((size_t)p.x << 4));
            acc.x = fmaf(val, bf2f_lo(u.x), acc.x);
            acc.y = fmaf(val, bf2f_hi(u.x), acc.y);
            acc.z = fmaf(val, bf2f_lo(u.y), acc.z);
            acc.w = fmaf(val, bf2f_hi(u.y), acc.w);
        }
    }

#pragma unroll
    for (int m = 4; m < 64; m <<= 1) {
        acc.x += __shfl_xor(acc.x, m, 64);
        acc.y += __shfl_xor(acc.y, m, 64);
        acc.z += __shfl_xor(acc.z, m, 64);
        acc.w += __shfl_xor(acc.w, m, 64);
    }

    if (slot == 0) {
        if (RELU) {
            acc.x = fmaxf(acc.x, 0.f); acc.y = fmaxf(acc.y, 0.f);
            acc.z = fmaxf(acc.z, 0.f); acc.w = fmaxf(acc.w, 0.f);
        }
        float* op = out + ((size_t)i * N + n) * DOUT + colq * 16 + 4 * ol;
        *reinterpret_cast<float4*>(op) = acc;
    }
}

extern "C" void kernel_launch(void* const* d_in, const int* in_sizes, int n_in,
                              void* d_out, int out_size, void* d_ws, size_t ws_size,
                              hipStream_t stream) {
    const float* feat      = (const float*)d_in[0];
    const int*   adj1_rows = (const int*)  d_in[1];
    const int*   adj1_cols = (const int*)  d_in[2];
    const float* adj1_vals = (const float*)d_in[3];
    const int*   adj2_rows = (const int*)  d_in[4];
    const int*   adj2_cols = (const int*)  d_in[5];
    const float* adj2_vals = (const float*)d_in[6];
    const float* W1        = (const float*)d_in[7];
    const float* W2        = (const float*)d_in[8];
    const float* W3        = (const float*)d_in[9];
    const float* W4        = (const float*)d_in[10];

    const int E = in_sizes[1] / 4;              // 500000
    const int F = in_sizes[7] / (4 * DOUT);     // 128
    const int N = in_sizes[0] / (2 * F);        // 50000
    const int M = 8 * N;
    const int nb1 = (M + 255) / 256;
    const int nw  = (N + WBINS - 1) / WBINS;
    const int chunkE = (E + CCH - 1) / CCH;

    auto align256 = [](size_t x) { return (x + 255) & ~(size_t)255; };

    const size_t cv_b   = align256((size_t)8 * E * sizeof(int2));        // 32 MB
    const size_t rp_b   = align256(((size_t)M + 8) * sizeof(int));       // 1.6 MB
    const size_t xwq_b  = align256((size_t)2 * 8 * N * 16 * sizeof(__hip_bfloat16)); // 25.6 MB
    const size_t ha_b   = align256((size_t)2 * N * DOUT * sizeof(float));            // 25.6 MB
    // Ha region hosts rank (8 MB) + cnt (1.6 MB) + partials during build.
    // XWq region hosts cnt3 (12.8 MB) during build.

    char* w = (char*)d_ws;
    int2* cv      = (int2*)w;  w += cv_b;
    int*  row_ptr = (int*)w;   w += rp_b;
    __hip_bfloat16* XWq = (__hip_bfloat16*)w;
    int*  cnt3    = (int*)w;   w += xwq_b;
    float* Ha     = (float*)w; w += ha_b;
    unsigned short* rank = (unsigned short*)Ha;
    int*  cnt     = (int*)((char*)Ha + align256((size_t)8 * E * sizeof(unsigned short)));
    int*  partials= (int*)((char*)cnt + align256((size_t)M * sizeof(int)));
    short* wb1    = (short*)w;                  // [2][8][4][64][8] = 64 KB
    short* wb2    = wb1 + 32768;                // KS=2 -> 32 KB each
    short* wb3    = wb2 + 16384;
    short* wb4    = wb3 + 16384;
    float* out    = (float*)d_out;

    // ---- W prep (independent of CSR build)
    k_wprep<<<16, 256, 0, stream>>>(W1, wb1, F);
    k_wprep<<<8, 256, 0, stream>>>(W2, wb2, DOUT);
    k_wprep<<<8, 256, 0, stream>>>(W3, wb3, DOUT);
    k_wprep<<<8, 256, 0, stream>>>(W4, wb4, DOUT);

    // ---- build CSR (segments 0..3 = adj1, 4..7 = adj2), no global atomics
    k_build<<<dim3(nw, 8, CCH), 1024, 0, stream>>>(adj1_rows, adj2_rows, E, chunkE, N, cnt3, rank);
    k_rowsum<<<dim3((N + 255) / 256, 8), 256, 0, stream>>>(cnt3, cnt, N);
    k_scan1<<<nb1, 256, 0, stream>>>(cnt, M, row_ptr, partials);
    k_scan2<<<1, 256, 0, stream>>>(partials, nb1);
    k_scan3<<<nb1, 256, 0, stream>>>(row_ptr, partials, M, 8 * E);
    k_fill<<<dim3((chunkE + 255) / 256, 8, CCH), 256, 0, stream>>>(
        adj1_rows, adj1_cols, adj1_vals, adj2_rows, adj2_cols, adj2_vals,
        E, chunkE, N, row_ptr, cnt3, rank, cv);

    const dim3 ggrid((N + 63) / 64, 2);
    const int  sblocks = 8 * ((N + 3) / 4);

    auto layer = [&](const float* Hin, int d_in, const short* wbl,
                     int set4, float* Hout, int relu_out) {
        if (d_in == 128) k_gemm<4><<<ggrid, 256, 0, stream>>>(Hin, wbl, XWq, N);
        else             k_gemm<2><<<ggrid, 256, 0, stream>>>(Hin, wbl, XWq, N);
        if (relu_out)
            k_spmm<1><<<sblocks, 256, 0, stream>>>(row_ptr, set4, cv,
                                                   (const unsigned short*)XWq, Hout, N);
        else
            k_spmm<0><<<sblocks, 256, 0, stream>>>(row_ptr, set4, cv,
                                                   (const unsigned short*)XWq, Hout, N);
    };

    layer(feat, F,    wb1, 0, Ha,  1);   // L1: adj1, relu into L2 input
    layer(Ha,   DOUT, wb2, 0, out, 1);   // L2: adj1, relu into L3 input
    layer(out,  DOUT, wb3, 4, Ha,  1);   // L3: adj2, relu into L4 input
    layer(Ha,   DOUT, wb4, 4, out, 0);   // L4: adj2 (final, no relu)
}

// Round 10
// 697.186 us; speedup vs baseline: 2.6026x; 1.0262x over previous
//
#include <hip/hip_runtime.h>
#include <hip/hip_bf16.h>

// Multi-relational GCN, 4 layers. Round 10:
//  - k_fill: XCD<->segment affinity (seg = blockIdx.x fastest) so each 4MB cv
//    slice fills inside one XCD's L2 (kills 4x write-line amplification)
//  - k_base: cnt3 += row_ptr in place after scan -> fill does ONE gather/edge
//  - MFMA gemm / merged spmm / chunked build byte-identical to round 9
// relation r = 2*i + j: dst type i = r>>1, src type j = r&1.
// Segments 0..3 = adj1 (layers 1-2), 4..7 = adj2 (layers 3-4).

#define DOUT 64
#define WBINS 12800   // 51.2 KB LDS histogram window
#define CCH   8       // edge chunks

typedef __attribute__((ext_vector_type(8))) short s16x8;
typedef __attribute__((ext_vector_type(4))) float f32x4;

__device__ __forceinline__ float bf2f_lo(unsigned u) {
    return __uint_as_float(u << 16);
}
__device__ __forceinline__ float bf2f_hi(unsigned u) {
    return __uint_as_float(u & 0xffff0000u);
}
__device__ __forceinline__ short f2bf(float x) {
    union { __hip_bfloat16 h; short s; } u;
    u.h = __float2bfloat16(x);
    return u.s;
}

// ---------------- build: per-(seg,window,chunk) LDS histogram + u16 rank
__global__ __launch_bounds__(1024) void k_build(
    const int* __restrict__ rows1, const int* __restrict__ rows2,
    int E, int chunkE, int N, int* __restrict__ cnt3, unsigned short* __restrict__ rank)
{
    __shared__ int bins[WBINS];
    const int w = blockIdx.x;
    const int s = blockIdx.y;
    const int c = blockIdx.z;
    const int lo = w * WBINS;
    const int hi = min(N, lo + WBINS);
    const int nb = hi - lo;
    if (nb <= 0) return;
    const int* rows = (s < 4) ? rows1 : rows2;
    const size_t base = (size_t)(s & 3) * E;
    const int e0 = c * chunkE;
    const int e1 = min(E, e0 + chunkE);

    for (int b = threadIdx.x; b < nb; b += 1024) bins[b] = 0;
    __syncthreads();

    for (int e = e0 + threadIdx.x; e < e1; e += 1024) {
        const int row = rows[base + e];
        if (row >= lo && row < hi) {
            const int r = atomicAdd(&bins[row - lo], 1);
            rank[(size_t)s * E + e] = (unsigned short)r;
        }
    }
    __syncthreads();

    for (int b = threadIdx.x; b < nb; b += 1024)
        cnt3[((size_t)(s * CCH + c)) * N + lo + b] = bins[b];
}

// ---------------- per-row: exclusive prefix over chunk counts (in place) + total
__global__ __launch_bounds__(256) void k_rowsum(
    int* __restrict__ cnt3, int* __restrict__ cnt, int N)
{
    const int row = blockIdx.x * 256 + threadIdx.x;
    const int s   = blockIdx.y;
    if (row >= N) return;
    int sum = 0;
#pragma unroll
    for (int c = 0; c < CCH; ++c) {
        const size_t idx = ((size_t)(s * CCH + c)) * N + row;
        const int v = cnt3[idx];
        cnt3[idx] = sum;
        sum += v;
    }
    cnt[(size_t)s * N + row] = sum;
}

// ---------------- exclusive scan, 3-kernel
__global__ __launch_bounds__(256) void k_scan1(
    const int* __restrict__ cnt, int M, int* __restrict__ out, int* __restrict__ partials)
{
    __shared__ int sm[256];
    const int i = blockIdx.x * 256 + threadIdx.x;
    const int x = (i < M) ? cnt[i] : 0;
    sm[threadIdx.x] = x;
    __syncthreads();
    for (int off = 1; off < 256; off <<= 1) {
        int t = (threadIdx.x >= off) ? sm[threadIdx.x - off] : 0;
        __syncthreads();
        sm[threadIdx.x] += t;
        __syncthreads();
    }
    if (i < M) out[i] = sm[threadIdx.x] - x;
    if (threadIdx.x == 255) partials[blockIdx.x] = sm[255];
}

__global__ __launch_bounds__(256) void k_scan2(int* __restrict__ partials, int nb)
{
    __shared__ int sm[256];
    __shared__ int carry_s;
    if (threadIdx.x == 0) carry_s = 0;
    __syncthreads();
    for (int base = 0; base < nb; base += 256) {
        const int i = base + threadIdx.x;
        const int x = (i < nb) ? partials[i] : 0;
        sm[threadIdx.x] = x;
        __syncthreads();
        for (int off = 1; off < 256; off <<= 1) {
            int t = (threadIdx.x >= off) ? sm[threadIdx.x - off] : 0;
            __syncthreads();
            sm[threadIdx.x] += t;
            __syncthreads();
        }
        const int carry = carry_s;
        const int incl  = sm[threadIdx.x];
        __syncthreads();
        if (i < nb) partials[i] = incl - x + carry;
        if (threadIdx.x == 255) carry_s = carry + incl;
        __syncthreads();
    }
}

__global__ __launch_bounds__(256) void k_scan3(
    int* __restrict__ row_ptr, const int* __restrict__ partials, int M, int total)
{
    const int i = blockIdx.x * 256 + threadIdx.x;
    if (i < M) row_ptr[i] += partials[blockIdx.x];
    if (i == 0) row_ptr[M] = total;
}

// ---------------- base fusion: cnt3[(s,c),row] += row_ptr[s,row]  (in place)
__global__ __launch_bounds__(256) void k_base(
    int* __restrict__ cnt3, const int* __restrict__ row_ptr, int N)
{
    const int row = blockIdx.x * 256 + threadIdx.x;
    const int s   = blockIdx.y;
    const int c   = blockIdx.z;
    if (row >= N) return;
    cnt3[((size_t)(s * CCH + c)) * N + row] += row_ptr[(size_t)s * N + row];
}

// ---------------- atomic-free CSR fill: pos = base3 + rank
// seg = blockIdx.x (fastest) -> consecutive blocks hit different segments ->
// round-robin XCD dispatch gives XCD k segment k: cv slice L2-local.
__global__ __launch_bounds__(256) void k_fill(
    const int* __restrict__ rows1, const int* __restrict__ cols1, const float* __restrict__ vals1,
    const int* __restrict__ rows2, const int* __restrict__ cols2, const float* __restrict__ vals2,
    int E, int chunkE, int N,
    const int* __restrict__ base3, const unsigned short* __restrict__ rank,
    int2* __restrict__ cv)
{
    const int s  = blockIdx.x;
    const int c  = blockIdx.z;
    const int el = blockIdx.y * 256 + threadIdx.x;
    const int e  = c * chunkE + el;
    if (el >= chunkE || e >= E) return;
    const int* rows   = (s < 4) ? rows1 : rows2;
    const int* cols   = (s < 4) ? cols1 : cols2;
    const float* vals = (s < 4) ? vals1 : vals2;
    const size_t idx  = (size_t)(s & 3) * E + e;
    const int row = rows[idx];
    const int pos = base3[((size_t)(s * CCH + c)) * N + row]
                  + (int)rank[(size_t)s * E + e];
    cv[pos] = make_int2(cols[idx], __float_as_int(vals[idx]));
}

// ---------------- W prep: bf16 B-fragments, layout [j][nt][ks][lane][8]
// nt = output 16-col tile (0..7): cols 0-63 = W[j] (dst 0), 64-127 = W[2+j].
__global__ __launch_bounds__(256) void k_wprep(
    const float* __restrict__ W, short* __restrict__ wb, int d_in)
{
    const int KS  = d_in >> 5;
    const int tid = blockIdx.x * 256 + threadIdx.x;
    if (tid >= 2 * 8 * KS * 64) return;
    const int l    = tid & 63;
    const int rest = tid >> 6;
    const int ks   = rest % KS;
    const int tt   = rest / KS;
    const int t    = tt & 7;
    const int j    = tt >> 3;
    const int r    = ((t >> 2) << 1) + j;            // t<4 -> j, t>=4 -> 2+j
    const int c    = ((t & 3) << 4) + (l & 15);      // col within the 64-wide W
    const int k0   = (ks << 5) + ((l >> 4) << 3);
    s16x8 v;
#pragma unroll
    for (int e = 0; e < 8; ++e)
        v[e] = f2bf(W[((size_t)r * d_in + k0 + e) * 64 + c]);
    *reinterpret_cast<s16x8*>(wb + (size_t)tid * 8) = v;
}

// ---------------- MFMA dense transform -> XWq[j][8][N][16] bf16
// Block: 64 rows x 128 cols, 4 waves x 16 rows. A per-lane from global (fp32
// -> bf16 in reg), B from prepped wb (L2). Epilogue: LDS repack -> uint4 stores.
template<int KS>
__global__ __launch_bounds__(256) void k_gemm(
    const float* __restrict__ H,           // [2, N, d_in]
    const short* __restrict__ wb,          // [2][8][KS][64][8] bf16 bits
    __hip_bfloat16* __restrict__ XWq,      // [2][8][N][16]
    int N)
{
    __shared__ __hip_bfloat16 lds_o[64][136];
    const int d_in = KS * 32;
    const int j    = blockIdx.y;
    const int wv   = threadIdx.x >> 6;
    const int lane = threadIdx.x & 63;
    const int row0 = blockIdx.x * 64;

    const int arow = row0 + wv * 16 + (lane & 15);
    const int rc   = (arow < N) ? arow : (N - 1);
    const float* Hb = H + (size_t)j * N * d_in + (size_t)rc * d_in + ((lane >> 4) << 3);

    // A fragments: lane holds row (lane&15), k = (lane>>4)*8 + e  (per ks)
    s16x8 a[KS];
#pragma unroll
    for (int ks = 0; ks < KS; ++ks) {
        union { float4 v; float f[4]; } f0, f1;
        f0.v = *reinterpret_cast<const float4*>(Hb + ks * 32);
        f1.v = *reinterpret_cast<const float4*>(Hb + ks * 32 + 4);
        s16x8 t;
#pragma unroll
        for (int e = 0; e < 4; ++e) { t[e] = f2bf(f0.f[e]); t[4 + e] = f2bf(f1.f[e]); }
        a[ks] = t;
    }

    f32x4 acc[8];
#pragma unroll
    for (int nt = 0; nt < 8; ++nt) acc[nt] = (f32x4){0.f, 0.f, 0.f, 0.f};

    const short* wbase = wb + ((size_t)j * 8 * KS * 64 + lane) * 8;
#pragma unroll
    for (int ks = 0; ks < KS; ++ks) {
#pragma unroll
        for (int nt = 0; nt < 8; ++nt) {
            const s16x8 b = *reinterpret_cast<const s16x8*>(
                wbase + (size_t)(nt * KS + ks) * 64 * 8);
            acc[nt] = __builtin_amdgcn_mfma_f32_16x16x32_bf16(a[ks], b, acc[nt], 0, 0, 0);
        }
    }

    // C/D layout: col = lane&15, row = (lane>>4)*4 + r
#pragma unroll
    for (int nt = 0; nt < 8; ++nt)
#pragma unroll
        for (int r = 0; r < 4; ++r)
            lds_o[wv * 16 + ((lane >> 4) << 2) + r][nt * 16 + (lane & 15)] =
                __float2bfloat16(acc[nt][r]);
    __syncthreads();

    const int t = threadIdx.x;
#pragma unroll
    for (int p = 0; p < 4; ++p) {
        const int r = p * 16 + (t >> 4);
        const int n = row0 + r;
        if (n < N) {
            const int g = t & 15;                      // 16B group: cols g*8..g*8+7
            const uint4 v = *reinterpret_cast<const uint4*>(&lds_o[r][g * 8]);
            *reinterpret_cast<uint4*>(
                (unsigned short*)XWq + ((size_t)(j * 8 + (g >> 1)) * N + n) * 16 + (g & 1) * 8) = v;
        }
    }
}

// ---------------- merged SpMM: one wave per (dst row, 16-col region), both
// relations accumulated. q = bid&7 -> XCD-local 1.6MB regions (js pair 3.2MB).
// slot = lane>>2 picks edge (16 edges/instr), ol = lane&3 picks 4 cols.
// RELU applies the next layer's input activation at store time.
template<int RELU>
__global__ __launch_bounds__(256) void k_spmm(
    const int* __restrict__ row_ptr, int set4,
    const int2* __restrict__ cv,
    const unsigned short* __restrict__ XWq,   // bf16 [2][8][N][16]
    float* __restrict__ out,                  // [2, N, 64]
    int N)
{
    const int bid    = blockIdx.x;
    const int q      = bid & 7;
    const int rowblk = bid >> 3;
    const int i    = q >> 2;
    const int colq = q & 3;
    const int wv   = threadIdx.x >> 6;
    const int n    = rowblk * 4 + wv;
    if (n >= N) return;
    const int lane = threadIdx.x & 63;
    const int slot = lane >> 2;
    const int ol   = lane & 3;

    float4 acc = make_float4(0.f, 0.f, 0.f, 0.f);

#pragma unroll
    for (int js = 0; js < 2; ++js) {
        const int seg = set4 + 2 * i + js;
        const int* rp = row_ptr + (size_t)seg * N;
        const int s = rp[n];
        const int e = rp[n + 1];
        const unsigned short* xw = XWq + ((size_t)(js * 8 + q) * N) * 16 + 4 * ol;

        for (int t0 = s; t0 < e; t0 += 16) {
            const int t  = t0 + slot;
            const bool v = (t < e);
            const int tc = v ? t : (e - 1);
            const int2 p = cv[tc];
            const float val = v ? __int_as_float(p.y) : 0.f;
            const uint2 u = *reinterpret_cast<const uint2*>(xw + ((size_t)p.x << 4));
            acc.x = fmaf(val, bf2f_lo(u.x), acc.x);
            acc.y = fmaf(val, bf2f_hi(u.x), acc.y);
            acc.z = fmaf(val, bf2f_lo(u.y), acc.z);
            acc.w = fmaf(val, bf2f_hi(u.y), acc.w);
        }
    }

#pragma unroll
    for (int m = 4; m < 64; m <<= 1) {
        acc.x += __shfl_xor(acc.x, m, 64);
        acc.y += __shfl_xor(acc.y, m, 64);
        acc.z += __shfl_xor(acc.z, m, 64);
        acc.w += __shfl_xor(acc.w, m, 64);
    }

    if (slot == 0) {
        if (RELU) {
            acc.x = fmaxf(acc.x, 0.f); acc.y = fmaxf(acc.y, 0.f);
            acc.z = fmaxf(acc.z, 0.f); acc.w = fmaxf(acc.w, 0.f);
        }
        float* op = out + ((size_t)i * N + n) * DOUT + colq * 16 + 4 * ol;
        *reinterpret_cast<float4*>(op) = acc;
    }
}

extern "C" void kernel_launch(void* const* d_in, const int* in_sizes, int n_in,
                              void* d_out, int out_size, void* d_ws, size_t ws_size,
                              hipStream_t stream) {
    const float* feat      = (const float*)d_in[0];
    const int*   adj1_rows = (const int*)  d_in[1];
    const int*   adj1_cols = (const int*)  d_in[2];
    const float* adj1_vals = (const float*)d_in[3];
    const int*   adj2_rows = (const int*)  d_in[4];
    const int*   adj2_cols = (const int*)  d_in[5];
    const float* adj2_vals = (const float*)d_in[6];
    const float* W1        = (const float*)d_in[7];
    const float* W2        = (const float*)d_in[8];
    const float* W3        = (const float*)d_in[9];
    const float* W4        = (const float*)d_in[10];

    const int E = in_sizes[1] / 4;              // 500000
    const int F = in_sizes[7] / (4 * DOUT);     // 128
    const int N = in_sizes[0] / (2 * F);        // 50000
    const int M = 8 * N;
    const int nb1 = (M + 255) / 256;
    const int nw  = (N + WBINS - 1) / WBINS;
    const int chunkE = (E + CCH - 1) / CCH;

    auto align256 = [](size_t x) { return (x + 255) & ~(size_t)255; };

    const size_t cv_b   = align256((size_t)8 * E * sizeof(int2));        // 32 MB
    const size_t rp_b   = align256(((size_t)M + 8) * sizeof(int));       // 1.6 MB
    const size_t xwq_b  = align256((size_t)2 * 8 * N * 16 * sizeof(__hip_bfloat16)); // 25.6 MB
    const size_t ha_b   = align256((size_t)2 * N * DOUT * sizeof(float));            // 25.6 MB
    // Ha region hosts rank (8 MB) + cnt (1.6 MB) + partials during build.
    // XWq region hosts cnt3/base3 (12.8 MB) during build.

    char* w = (char*)d_ws;
    int2* cv      = (int2*)w;  w += cv_b;
    int*  row_ptr = (int*)w;   w += rp_b;
    __hip_bfloat16* XWq = (__hip_bfloat16*)w;
    int*  cnt3    = (int*)w;   w += xwq_b;
    float* Ha     = (float*)w; w += ha_b;
    unsigned short* rank = (unsigned short*)Ha;
    int*  cnt     = (int*)((char*)Ha + align256((size_t)8 * E * sizeof(unsigned short)));
    int*  partials= (int*)((char*)cnt + align256((size_t)M * sizeof(int)));
    short* wb1    = (short*)w;                  // [2][8][4][64][8] = 64 KB
    short* wb2    = wb1 + 32768;                // KS=2 -> 32 KB each
    short* wb3    = wb2 + 16384;
    short* wb4    = wb3 + 16384;
    float* out    = (float*)d_out;

    // ---- W prep (independent of CSR build)
    k_wprep<<<16, 256, 0, stream>>>(W1, wb1, F);
    k_wprep<<<8, 256, 0, stream>>>(W2, wb2, DOUT);
    k_wprep<<<8, 256, 0, stream>>>(W3, wb3, DOUT);
    k_wprep<<<8, 256, 0, stream>>>(W4, wb4, DOUT);

    // ---- build CSR (segments 0..3 = adj1, 4..7 = adj2), no global atomics
    k_build<<<dim3(nw, 8, CCH), 1024, 0, stream>>>(adj1_rows, adj2_rows, E, chunkE, N, cnt3, rank);
    k_rowsum<<<dim3((N + 255) / 256, 8), 256, 0, stream>>>(cnt3, cnt, N);
    k_scan1<<<nb1, 256, 0, stream>>>(cnt, M, row_ptr, partials);
    k_scan2<<<1, 256, 0, stream>>>(partials, nb1);
    k_scan3<<<nb1, 256, 0, stream>>>(row_ptr, partials, M, 8 * E);
    k_base<<<dim3((N + 255) / 256, 8, CCH), 256, 0, stream>>>(cnt3, row_ptr, N);
    k_fill<<<dim3(8, (chunkE + 255) / 256, CCH), 256, 0, stream>>>(
        adj1_rows, adj1_cols, adj1_vals, adj2_rows, adj2_cols, adj2_vals,
        E, chunkE, N, cnt3, rank, cv);

    const dim3 ggrid((N + 63) / 64, 2);
    const int  sblocks = 8 * ((N + 3) / 4);

    auto layer = [&](const float* Hin, int d_in, const short* wbl,
                     int set4, float* Hout, int relu_out) {
        if (d_in == 128) k_gemm<4><<<ggrid, 256, 0, stream>>>(Hin, wbl, XWq, N);
        else             k_gemm<2><<<ggrid, 256, 0, stream>>>(Hin, wbl, XWq, N);
        if (relu_out)
            k_spmm<1><<<sblocks, 256, 0, stream>>>(row_ptr, set4, cv,
                                                   (const unsigned short*)XWq, Hout, N);
        else
            k_spmm<0><<<sblocks, 256, 0, stream>>>(row_ptr, set4, cv,
                                                   (const unsigned short*)XWq, Hout, N);
    };

    layer(feat, F,    wb1, 0, Ha,  1);   // L1: adj1, relu into L2 input
    layer(Ha,   DOUT, wb2, 0, out, 1);   // L2: adj1, relu into L3 input
    layer(out,  DOUT, wb3, 4, Ha,  1);   // L3: adj2, relu into L4 input
    layer(Ha,   DOUT, wb4, 4, out, 0);   // L4: adj2 (final, no relu)
}

// Round 11
// 398.365 us; speedup vs baseline: 4.5548x; 1.7501x over previous
//
#include <hip/hip_runtime.h>
#include <hip/hip_bf16.h>

// Multi-relational GCN, 4 layers. Round 11:
//  - spmm: ONE wave per (dst row): XW re-laid as [j][i][N][64] (128B/edge,
//    contiguous), 8 edges/iter x 8 col-octet lanes (uint4 = 8 bf16 cols/lane),
//    fixed costs (row_ptr, reduce, store) paid once per row (was 4x)
//  - gemm epilogue stores to the new layout; all else identical to round 10
// relation r = 2*i + j: dst type i = r>>1, src type j = r&1.
// Segments 0..3 = adj1 (layers 1-2), 4..7 = adj2 (layers 3-4).

#define DOUT 64
#define WBINS 12800   // 51.2 KB LDS histogram window
#define CCH   8       // edge chunks

typedef __attribute__((ext_vector_type(8))) short s16x8;
typedef __attribute__((ext_vector_type(4))) float f32x4;

__device__ __forceinline__ float bf2f_lo(unsigned u) {
    return __uint_as_float(u << 16);
}
__device__ __forceinline__ float bf2f_hi(unsigned u) {
    return __uint_as_float(u & 0xffff0000u);
}
__device__ __forceinline__ short f2bf(float x) {
    union { __hip_bfloat16 h; short s; } u;
    u.h = __float2bfloat16(x);
    return u.s;
}

// ---------------- build: per-(seg,window,chunk) LDS histogram + u16 rank
__global__ __launch_bounds__(1024) void k_build(
    const int* __restrict__ rows1, const int* __restrict__ rows2,
    int E, int chunkE, int N, int* __restrict__ cnt3, unsigned short* __restrict__ rank)
{
    __shared__ int bins[WBINS];
    const int w = blockIdx.x;
    const int s = blockIdx.y;
    const int c = blockIdx.z;
    const int lo = w * WBINS;
    const int hi = min(N, lo + WBINS);
    const int nb = hi - lo;
    if (nb <= 0) return;
    const int* rows = (s < 4) ? rows1 : rows2;
    const size_t base = (size_t)(s & 3) * E;
    const int e0 = c * chunkE;
    const int e1 = min(E, e0 + chunkE);

    for (int b = threadIdx.x; b < nb; b += 1024) bins[b] = 0;
    __syncthreads();

    for (int e = e0 + threadIdx.x; e < e1; e += 1024) {
        const int row = rows[base + e];
        if (row >= lo && row < hi) {
            const int r = atomicAdd(&bins[row - lo], 1);
            rank[(size_t)s * E + e] = (unsigned short)r;
        }
    }
    __syncthreads();

    for (int b = threadIdx.x; b < nb; b += 1024)
        cnt3[((size_t)(s * CCH + c)) * N + lo + b] = bins[b];
}

// ---------------- per-row: exclusive prefix over chunk counts (in place) + total
__global__ __launch_bounds__(256) void k_rowsum(
    int* __restrict__ cnt3, int* __restrict__ cnt, int N)
{
    const int row = blockIdx.x * 256 + threadIdx.x;
    const int s   = blockIdx.y;
    if (row >= N) return;
    int sum = 0;
#pragma unroll
    for (int c = 0; c < CCH; ++c) {
        const size_t idx = ((size_t)(s * CCH + c)) * N + row;
        const int v = cnt3[idx];
        cnt3[idx] = sum;
        sum += v;
    }
    cnt[(size_t)s * N + row] = sum;
}

// ---------------- exclusive scan, 3-kernel
__global__ __launch_bounds__(256) void k_scan1(
    const int* __restrict__ cnt, int M, int* __restrict__ out, int* __restrict__ partials)
{
    __shared__ int sm[256];
    const int i = blockIdx.x * 256 + threadIdx.x;
    const int x = (i < M) ? cnt[i] : 0;
    sm[threadIdx.x] = x;
    __syncthreads();
    for (int off = 1; off < 256; off <<= 1) {
        int t = (threadIdx.x >= off) ? sm[threadIdx.x - off] : 0;
        __syncthreads();
        sm[threadIdx.x] += t;
        __syncthreads();
    }
    if (i < M) out[i] = sm[threadIdx.x] - x;
    if (threadIdx.x == 255) partials[blockIdx.x] = sm[255];
}

__global__ __launch_bounds__(256) void k_scan2(int* __restrict__ partials, int nb)
{
    __shared__ int sm[256];
    __shared__ int carry_s;
    if (threadIdx.x == 0) carry_s = 0;
    __syncthreads();
    for (int base = 0; base < nb; base += 256) {
        const int i = base + threadIdx.x;
        const int x = (i < nb) ? partials[i] : 0;
        sm[threadIdx.x] = x;
        __syncthreads();
        for (int off = 1; off < 256; off <<= 1) {
            int t = (threadIdx.x >= off) ? sm[threadIdx.x - off] : 0;
            __syncthreads();
            sm[threadIdx.x] += t;
            __syncthreads();
        }
        const int carry = carry_s;
        const int incl  = sm[threadIdx.x];
        __syncthreads();
        if (i < nb) partials[i] = incl - x + carry;
        if (threadIdx.x == 255) carry_s = carry + incl;
        __syncthreads();
    }
}

__global__ __launch_bounds__(256) void k_scan3(
    int* __restrict__ row_ptr, const int* __restrict__ partials, int M, int total)
{
    const int i = blockIdx.x * 256 + threadIdx.x;
    if (i < M) row_ptr[i] += partials[blockIdx.x];
    if (i == 0) row_ptr[M] = total;
}

// ---------------- base fusion: cnt3[(s,c),row] += row_ptr[s,row]  (in place)
__global__ __launch_bounds__(256) void k_base(
    int* __restrict__ cnt3, const int* __restrict__ row_ptr, int N)
{
    const int row = blockIdx.x * 256 + threadIdx.x;
    const int s   = blockIdx.y;
    const int c   = blockIdx.z;
    if (row >= N) return;
    cnt3[((size_t)(s * CCH + c)) * N + row] += row_ptr[(size_t)s * N + row];
}

// ---------------- atomic-free CSR fill: pos = base3 + rank (seg fastest -> XCD)
__global__ __launch_bounds__(256) void k_fill(
    const int* __restrict__ rows1, const int* __restrict__ cols1, const float* __restrict__ vals1,
    const int* __restrict__ rows2, const int* __restrict__ cols2, const float* __restrict__ vals2,
    int E, int chunkE, int N,
    const int* __restrict__ base3, const unsigned short* __restrict__ rank,
    int2* __restrict__ cv)
{
    const int s  = blockIdx.x;
    const int c  = blockIdx.z;
    const int el = blockIdx.y * 256 + threadIdx.x;
    const int e  = c * chunkE + el;
    if (el >= chunkE || e >= E) return;
    const int* rows   = (s < 4) ? rows1 : rows2;
    const int* cols   = (s < 4) ? cols1 : cols2;
    const float* vals = (s < 4) ? vals1 : vals2;
    const size_t idx  = (size_t)(s & 3) * E + e;
    const int row = rows[idx];
    const int pos = base3[((size_t)(s * CCH + c)) * N + row]
                  + (int)rank[(size_t)s * E + e];
    cv[pos] = make_int2(cols[idx], __float_as_int(vals[idx]));
}

// ---------------- W prep: bf16 B-fragments, layout [j][nt][ks][lane][8]
// nt = output 16-col tile (0..7): cols 0-63 = W[j] (dst 0), 64-127 = W[2+j].
__global__ __launch_bounds__(256) void k_wprep(
    const float* __restrict__ W, short* __restrict__ wb, int d_in)
{
    const int KS  = d_in >> 5;
    const int tid = blockIdx.x * 256 + threadIdx.x;
    if (tid >= 2 * 8 * KS * 64) return;
    const int l    = tid & 63;
    const int rest = tid >> 6;
    const int ks   = rest % KS;
    const int tt   = rest / KS;
    const int t    = tt & 7;
    const int j    = tt >> 3;
    const int r    = ((t >> 2) << 1) + j;            // t<4 -> j, t>=4 -> 2+j
    const int c    = ((t & 3) << 4) + (l & 15);      // col within the 64-wide W
    const int k0   = (ks << 5) + ((l >> 4) << 3);
    s16x8 v;
#pragma unroll
    for (int e = 0; e < 8; ++e)
        v[e] = f2bf(W[((size_t)r * d_in + k0 + e) * 64 + c]);
    *reinterpret_cast<s16x8*>(wb + (size_t)tid * 8) = v;
}

// ---------------- MFMA dense transform -> XW[j][i][N][64] bf16
// Block: 64 rows x 128 cols, 4 waves x 16 rows. A per-lane from global (fp32
// -> bf16 in reg), B from prepped wb (L2). Epilogue: LDS repack -> uint4 stores.
template<int KS>
__global__ __launch_bounds__(256) void k_gemm(
    const float* __restrict__ H,           // [2, N, d_in]
    const short* __restrict__ wb,          // [2][8][KS][64][8] bf16 bits
    __hip_bfloat16* __restrict__ XW,       // [2][2][N][64]
    int N)
{
    __shared__ __hip_bfloat16 lds_o[64][136];
    const int d_in = KS * 32;
    const int j    = blockIdx.y;
    const int wv   = threadIdx.x >> 6;
    const int lane = threadIdx.x & 63;
    const int row0 = blockIdx.x * 64;

    const int arow = row0 + wv * 16 + (lane & 15);
    const int rc   = (arow < N) ? arow : (N - 1);
    const float* Hb = H + (size_t)j * N * d_in + (size_t)rc * d_in + ((lane >> 4) << 3);

    // A fragments: lane holds row (lane&15), k = (lane>>4)*8 + e  (per ks)
    s16x8 a[KS];
#pragma unroll
    for (int ks = 0; ks < KS; ++ks) {
        union { float4 v; float f[4]; } f0, f1;
        f0.v = *reinterpret_cast<const float4*>(Hb + ks * 32);
        f1.v = *reinterpret_cast<const float4*>(Hb + ks * 32 + 4);
        s16x8 t;
#pragma unroll
        for (int e = 0; e < 4; ++e) { t[e] = f2bf(f0.f[e]); t[4 + e] = f2bf(f1.f[e]); }
        a[ks] = t;
    }

    f32x4 acc[8];
#pragma unroll
    for (int nt = 0; nt < 8; ++nt) acc[nt] = (f32x4){0.f, 0.f, 0.f, 0.f};

    const short* wbase = wb + ((size_t)j * 8 * KS * 64 + lane) * 8;
#pragma unroll
    for (int ks = 0; ks < KS; ++ks) {
#pragma unroll
        for (int nt = 0; nt < 8; ++nt) {
            const s16x8 b = *reinterpret_cast<const s16x8*>(
                wbase + (size_t)(nt * KS + ks) * 64 * 8);
            acc[nt] = __builtin_amdgcn_mfma_f32_16x16x32_bf16(a[ks], b, acc[nt], 0, 0, 0);
        }
    }

    // C/D layout: col = lane&15, row = (lane>>4)*4 + r
#pragma unroll
    for (int nt = 0; nt < 8; ++nt)
#pragma unroll
        for (int r = 0; r < 4; ++r)
            lds_o[wv * 16 + ((lane >> 4) << 2) + r][nt * 16 + (lane & 15)] =
                __float2bfloat16(acc[nt][r]);
    __syncthreads();

    // repack: thread t -> row r = p*16 + (t>>4); 16B group g = t&15:
    // i = g>>3, col-octet c = (g&7)*8  ->  XW[(j*2+i)][n][c..c+7]
    const int t = threadIdx.x;
#pragma unroll
    for (int p = 0; p < 4; ++p) {
        const int r = p * 16 + (t >> 4);
        const int n = row0 + r;
        if (n < N) {
            const int g = t & 15;
            const uint4 v = *reinterpret_cast<const uint4*>(&lds_o[r][g * 8]);
            *reinterpret_cast<uint4*>(
                (unsigned short*)XW + ((size_t)(j * 2 + (g >> 3)) * N + n) * 64 + (g & 7) * 8) = v;
        }
    }
}

// ---------------- SpMM: ONE wave per dst row; both relations accumulated.
// slot = lane>>3 picks edge (8 edges/iter), ol = lane&7 picks col-octet:
// lane loads uint4 = 8 bf16 cols of the edge's 128B-contiguous XW row.
template<int RELU>
__global__ __launch_bounds__(256) void k_spmm(
    const int* __restrict__ row_ptr, int set4,
    const int2* __restrict__ cv,
    const unsigned short* __restrict__ XW,    // bf16 [2][2][N][64]
    float* __restrict__ out,                  // [2, N, 64]
    int N)
{
    const int i    = blockIdx.y;
    const int wv   = threadIdx.x >> 6;
    const int n    = blockIdx.x * 4 + wv;
    if (n >= N) return;
    const int lane = threadIdx.x & 63;
    const int slot = lane >> 3;
    const int ol   = lane & 7;

    float acc[8];
#pragma unroll
    for (int k = 0; k < 8; ++k) acc[k] = 0.f;

#pragma unroll
    for (int js = 0; js < 2; ++js) {
        const int seg = set4 + 2 * i + js;
        const int* rp = row_ptr + (size_t)seg * N;
        const int s = rp[n];
        const int e = rp[n + 1];
        const unsigned short* xw = XW + ((size_t)(js * 2 + i) * N) * 64 + ol * 8;

        for (int t0 = s; t0 < e; t0 += 8) {
            const int t  = t0 + slot;
            const bool v = (t < e);
            const int tc = v ? t : (e - 1);
            const int2 p = cv[tc];
            const float val = v ? __int_as_float(p.y) : 0.f;
            const uint4 u = *reinterpret_cast<const uint4*>(xw + ((size_t)p.x << 6));
            acc[0] = fmaf(val, bf2f_lo(u.x), acc[0]);
            acc[1] = fmaf(val, bf2f_hi(u.x), acc[1]);
            acc[2] = fmaf(val, bf2f_lo(u.y), acc[2]);
            acc[3] = fmaf(val, bf2f_hi(u.y), acc[3]);
            acc[4] = fmaf(val, bf2f_lo(u.z), acc[4]);
            acc[5] = fmaf(val, bf2f_hi(u.z), acc[5]);
            acc[6] = fmaf(val, bf2f_lo(u.w), acc[6]);
            acc[7] = fmaf(val, bf2f_hi(u.w), acc[7]);
        }
    }

    // reduce across the 8 slots (lanes ol, ol+8, ..., ol+56)
#pragma unroll
    for (int m = 8; m < 64; m <<= 1) {
#pragma unroll
        for (int k = 0; k < 8; ++k) acc[k] += __shfl_xor(acc[k], m, 64);
    }

    if (slot == 0) {
        if (RELU) {
#pragma unroll
            for (int k = 0; k < 8; ++k) acc[k] = fmaxf(acc[k], 0.f);
        }
        float* op = out + ((size_t)i * N + n) * DOUT + ol * 8;
        *reinterpret_cast<float4*>(op)     = make_float4(acc[0], acc[1], acc[2], acc[3]);
        *reinterpret_cast<float4*>(op + 4) = make_float4(acc[4], acc[5], acc[6], acc[7]);
    }
}

extern "C" void kernel_launch(void* const* d_in, const int* in_sizes, int n_in,
                              void* d_out, int out_size, void* d_ws, size_t ws_size,
                              hipStream_t stream) {
    const float* feat      = (const float*)d_in[0];
    const int*   adj1_rows = (const int*)  d_in[1];
    const int*   adj1_cols = (const int*)  d_in[2];
    const float* adj1_vals = (const float*)d_in[3];
    const int*   adj2_rows = (const int*)  d_in[4];
    const int*   adj2_cols = (const int*)  d_in[5];
    const float* adj2_vals = (const float*)d_in[6];
    const float* W1        = (const float*)d_in[7];
    const float* W2        = (const float*)d_in[8];
    const float* W3        = (const float*)d_in[9];
    const float* W4        = (const float*)d_in[10];

    const int E = in_sizes[1] / 4;              // 500000
    const int F = in_sizes[7] / (4 * DOUT);     // 128
    const int N = in_sizes[0] / (2 * F);        // 50000
    const int M = 8 * N;
    const int nb1 = (M + 255) / 256;
    const int nw  = (N + WBINS - 1) / WBINS;
    const int chunkE = (E + CCH - 1) / CCH;

    auto align256 = [](size_t x) { return (x + 255) & ~(size_t)255; };

    const size_t cv_b   = align256((size_t)8 * E * sizeof(int2));        // 32 MB
    const size_t rp_b   = align256(((size_t)M + 8) * sizeof(int));       // 1.6 MB
    const size_t xw_b   = align256((size_t)2 * 2 * N * 64 * sizeof(__hip_bfloat16)); // 25.6 MB
    const size_t ha_b   = align256((size_t)2 * N * DOUT * sizeof(float));            // 25.6 MB
    // Ha region hosts rank (8 MB) + cnt (1.6 MB) + partials during build.
    // XW region hosts cnt3/base3 (12.8 MB) during build.

    char* w = (char*)d_ws;
    int2* cv      = (int2*)w;  w += cv_b;
    int*  row_ptr = (int*)w;   w += rp_b;
    __hip_bfloat16* XW = (__hip_bfloat16*)w;
    int*  cnt3    = (int*)w;   w += xw_b;
    float* Ha     = (float*)w; w += ha_b;
    unsigned short* rank = (unsigned short*)Ha;
    int*  cnt     = (int*)((char*)Ha + align256((size_t)8 * E * sizeof(unsigned short)));
    int*  partials= (int*)((char*)cnt + align256((size_t)M * sizeof(int)));
    short* wb1    = (short*)w;                  // [2][8][4][64][8] = 64 KB
    short* wb2    = wb1 + 32768;                // KS=2 -> 32 KB each
    short* wb3    = wb2 + 16384;
    short* wb4    = wb3 + 16384;
    float* out    = (float*)d_out;

    // ---- W prep (independent of CSR build)
    k_wprep<<<16, 256, 0, stream>>>(W1, wb1, F);
    k_wprep<<<8, 256, 0, stream>>>(W2, wb2, DOUT);
    k_wprep<<<8, 256, 0, stream>>>(W3, wb3, DOUT);
    k_wprep<<<8, 256, 0, stream>>>(W4, wb4, DOUT);

    // ---- build CSR (segments 0..3 = adj1, 4..7 = adj2), no global atomics
    k_build<<<dim3(nw, 8, CCH), 1024, 0, stream>>>(adj1_rows, adj2_rows, E, chunkE, N, cnt3, rank);
    k_rowsum<<<dim3((N + 255) / 256, 8), 256, 0, stream>>>(cnt3, cnt, N);
    k_scan1<<<nb1, 256, 0, stream>>>(cnt, M, row_ptr, partials);
    k_scan2<<<1, 256, 0, stream>>>(partials, nb1);
    k_scan3<<<nb1, 256, 0, stream>>>(row_ptr, partials, M, 8 * E);
    k_base<<<dim3((N + 255) / 256, 8, CCH), 256, 0, stream>>>(cnt3, row_ptr, N);
    k_fill<<<dim3(8, (chunkE + 255) / 256, CCH), 256, 0, stream>>>(
        adj1_rows, adj1_cols, adj1_vals, adj2_rows, adj2_cols, adj2_vals,
        E, chunkE, N, cnt3, rank, cv);

    const dim3 ggrid((N + 63) / 64, 2);
    const dim3 sgrid((N + 3) / 4, 2);

    auto layer = [&](const float* Hin, int d_in, const short* wbl,
                     int set4, float* Hout, int relu_out) {
        if (d_in == 128) k_gemm<4><<<ggrid, 256, 0, stream>>>(Hin, wbl, XW, N);
        else             k_gemm<2><<<ggrid, 256, 0, stream>>>(Hin, wbl, XW, N);
        if (relu_out)
            k_spmm<1><<<sgrid, 256, 0, stream>>>(row_ptr, set4, cv,
                                                 (const unsigned short*)XW, Hout, N);
        else
            k_spmm<0><<<sgrid, 256, 0, stream>>>(row_ptr, set4, cv,
                                                 (const unsigned short*)XW, Hout, N);
    };

    layer(feat, F,    wb1, 0, Ha,  1);   // L1: adj1, relu into L2 input
    layer(Ha,   DOUT, wb2, 0, out, 1);   // L2: adj1, relu into L3 input
    layer(out,  DOUT, wb3, 4, Ha,  1);   // L3: adj2, relu into L4 input
    layer(Ha,   DOUT, wb4, 4, out, 0);   // L4: adj2 (final, no relu)
}